// Round 1
// baseline (591.734 us; speedup 1.0000x reference)
//
#include <hip/hip_runtime.h>
#include <hip/hip_bf16.h>
#include <stdint.h>

#define T_SEQ 2048
#define CDIM  2048
#define NHEAD 16
#define DHEAD 128
#define BT    4096   // B*T
#define BHT   32     // B*H

typedef __bf16 bf16x8_t __attribute__((ext_vector_type(8)));
typedef float  f32x4_t  __attribute__((ext_vector_type(4)));
typedef unsigned short u16x8_t __attribute__((ext_vector_type(8)));

__device__ __forceinline__ unsigned short f2bf(float f){
  unsigned int u = __float_as_uint(f);
  u += 0x7fffu + ((u >> 16) & 1u);
  return (unsigned short)(u >> 16);
}
__device__ __forceinline__ float bf2f(unsigned short h){
  return __uint_as_float(((unsigned int)h) << 16);
}

// ---------------- cast x (f32 -> bf16) ----------------
__global__ __launch_bounds__(256) void cast_f32_bf16(const float* __restrict__ in,
                                                     unsigned short* __restrict__ out, int n){
  int i = (blockIdx.x*256 + threadIdx.x)*8;
  if (i >= n) return;
  float4 a = *(const float4*)(in + i);
  float4 b = *(const float4*)(in + i + 4);
  u16x8_t o;
  o[0]=f2bf(a.x); o[1]=f2bf(a.y); o[2]=f2bf(a.z); o[3]=f2bf(a.w);
  o[4]=f2bf(b.x); o[5]=f2bf(b.y); o[6]=f2bf(b.z); o[7]=f2bf(b.w);
  *(u16x8_t*)(out + i) = o;
}

// ---------------- transpose + cast W (f32 [K][N] -> bf16 [N][K]) ----------------
__global__ __launch_bounds__(256) void transpose_cast(const float* __restrict__ W,
                                                      unsigned short* __restrict__ Wt){
  __shared__ float tile[32][33];
  int n0 = blockIdx.x*32, k0 = blockIdx.y*32;
  int tx = threadIdx.x, ty = threadIdx.y;  // 32 x 8
  #pragma unroll
  for (int i=0;i<32;i+=8)
    tile[ty+i][tx] = W[(size_t)(k0+ty+i)*CDIM + n0 + tx];
  __syncthreads();
  #pragma unroll
  for (int i=0;i<32;i+=8)
    Wt[(size_t)(n0+ty+i)*CDIM + k0 + tx] = f2bf(tile[tx][ty+i]);
}

// ---------------- bf16 MFMA GEMM: C[M][N] = A[M][K] * Bt[N][K]^T ----------------
// MODE 0: bf16 plain row-major; MODE 1: bf16 scatter to (B,H,T,D); MODE 2: f32 plain
template<int MODE>
__global__ __launch_bounds__(256) void gemm_bt(const unsigned short* __restrict__ A,
                                               const unsigned short* __restrict__ Bt,
                                               void* __restrict__ Cout,
                                               int M, int N, int K){
  __shared__ unsigned short As[128*32];
  __shared__ unsigned short Bs[128*32];
  const int m0 = blockIdx.y*128, n0 = blockIdx.x*128;
  const int tid = threadIdx.x;
  const int lane = tid & 63, wv = tid >> 6;
  const int g = lane >> 4, qi = lane & 15;
  const int wm = (wv >> 1)*64, wn = (wv & 1)*64;
  f32x4_t acc[4][4] = {};
  for (int k0 = 0; k0 < K; k0 += 32){
    __syncthreads();
    #pragma unroll
    for (int i=0;i<2;i++){
      int ci = i*256 + tid;
      int row = ci >> 2, kc = ci & 3;
      __builtin_amdgcn_global_load_lds(
        (const __attribute__((address_space(1))) void*)(A + (size_t)(m0+row)*K + k0 + kc*8),
        (__attribute__((address_space(3))) void*)(As + ci*8), 16, 0, 0);
      __builtin_amdgcn_global_load_lds(
        (const __attribute__((address_space(1))) void*)(Bt + (size_t)(n0+row)*K + k0 + kc*8),
        (__attribute__((address_space(3))) void*)(Bs + ci*8), 16, 0, 0);
    }
    __syncthreads();
    bf16x8_t af[4], bfr[4];
    #pragma unroll
    for (int mi=0;mi<4;mi++)
      af[mi] = *reinterpret_cast<const bf16x8_t*>(As + (wm + mi*16 + qi)*32 + g*8);
    #pragma unroll
    for (int ni=0;ni<4;ni++)
      bfr[ni] = *reinterpret_cast<const bf16x8_t*>(Bs + (wn + ni*16 + qi)*32 + g*8);
    #pragma unroll
    for (int mi=0;mi<4;mi++){
      #pragma unroll
      for (int ni=0;ni<4;ni++){
        acc[mi][ni] = __builtin_amdgcn_mfma_f32_16x16x32_bf16(af[mi], bfr[ni], acc[mi][ni], 0, 0, 0);
      }
    }
  }
  #pragma unroll
  for (int mi=0;mi<4;mi++){
    #pragma unroll
    for (int ni=0;ni<4;ni++){
      #pragma unroll
      for (int r=0;r<4;r++){
        int mm = m0 + wm + mi*16 + 4*g + r;
        int nn = n0 + wn + ni*16 + qi;
        float v = acc[mi][ni][r];
        if (MODE == 2){
          ((float*)Cout)[(size_t)mm*N + nn] = v;
        } else if (MODE == 0){
          ((unsigned short*)Cout)[(size_t)mm*N + nn] = f2bf(v);
        } else {
          int b = mm >> 11, t = mm & (T_SEQ-1);
          int hh = nn >> 7, d = nn & (DHEAD-1);
          ((unsigned short*)Cout)[(((size_t)b*NHEAD + hh)*T_SEQ + t)*DHEAD + d] = f2bf(v);
        }
      }
    }
  }
}

// ---------------- gates: lam/logit/log_fgate per (b,t,h) ----------------
__global__ __launch_bounds__(256) void gates_kernel(const float* __restrict__ x,
    const float* __restrict__ fgw, const float* __restrict__ fgb,
    const float* __restrict__ wlam, float* __restrict__ lfg){
  __shared__ float xs[2048];
  __shared__ float part[256];
  const int row = blockIdx.x;     // b*T + t
  const int tid = threadIdx.x;
  const float* xp = x + (size_t)row*CDIM;
  #pragma unroll
  for (int i=0;i<2;i++)
    *(float4*)(xs + (i*256+tid)*4) = *(const float4*)(xp + (i*256+tid)*4);
  __syncthreads();
  const int col = tid & 31;       // 0-15: fgate, 16-31: lambda
  const int seg = tid >> 5;       // 0..7
  const float* W = (col < 16) ? fgw : wlam;
  const int h = col & 15;
  float acc = 0.f;
  for (int k = seg*256; k < seg*256 + 256; ++k)
    acc = fmaf(xs[k], W[k*16 + h], acc);
  part[tid] = acc;
  __syncthreads();
  for (int s=4; s>=1; s>>=1){
    if (seg < s) part[tid] += part[tid + s*32];
    __syncthreads();
  }
  if (tid < 16){
    float df = part[tid];
    float dl = part[16 + tid];
    float lam = (dl > 0.f) ? (dl + 1.f) : __expf(dl);   // elu + 1
    float logit = (df + fgb[tid]) * lam;
    float ls = fminf(logit, 0.f) - log1pf(__expf(-fabsf(logit))); // log_sigmoid
    float lf = ls / (lam + 0.001f);
    int b = row >> 11, t = row & (T_SEQ-1);
    lfg[((size_t)b*NHEAD + tid)*T_SEQ + t] = lf;
  }
}

// ---------------- inclusive cumsum along T per (b,h) ----------------
__global__ __launch_bounds__(256) void cumsum_kernel(const float* __restrict__ lfg,
                                                     float* __restrict__ cumF){
  __shared__ float sums[256];
  const int bh = blockIdx.x;
  const float* in = lfg + (size_t)bh*T_SEQ;
  float* out = cumF + (size_t)bh*T_SEQ;
  const int tid = threadIdx.x;
  float4 a = *(const float4*)(in + tid*8);
  float4 b = *(const float4*)(in + tid*8 + 4);
  float v[8] = {a.x,a.y,a.z,a.w,b.x,b.y,b.z,b.w};
  float run = 0.f;
  #pragma unroll
  for (int e=0;e<8;e++) run += v[e];
  sums[tid] = run;
  __syncthreads();
  for (int off=1; off<256; off<<=1){
    float y = (tid >= off) ? sums[tid-off] : 0.f;
    __syncthreads();
    sums[tid] += y;
    __syncthreads();
  }
  float acc = sums[tid] - run;  // exclusive prefix
  float o[8];
  #pragma unroll
  for (int e=0;e<8;e++){ acc += v[e]; o[e] = acc; }
  *(float4*)(out + tid*8)     = make_float4(o[0],o[1],o[2],o[3]);
  *(float4*)(out + tid*8 + 4) = make_float4(o[4],o[5],o[6],o[7]);
}

// ---------------- in-place RoPE + RMSNorm on (B*H, T, D) bf16 ----------------
__global__ __launch_bounds__(256) void rope_rms(unsigned short* __restrict__ X,
    const float* __restrict__ cosT, const float* __restrict__ sinT){
  const int tid = threadIdx.x, lane = tid & 63, wv = tid >> 6;
  const int idx = blockIdx.x*4 + wv;        // (b*H + h)*T + t
  const int t = idx & (T_SEQ-1);
  unsigned short* xp = X + (size_t)idx*DHEAD;
  float x1 = bf2f(xp[lane]);
  float x2 = bf2f(xp[lane+64]);
  float c = cosT[t*64 + lane];
  float s = sinT[t*64 + lane];
  float o1 = x1*c + x2*s;
  float o2 = x2*c - x1*s;
  float ss = o1*o1 + o2*o2;
  #pragma unroll
  for (int off=1; off<64; off<<=1) ss += __shfl_xor(ss, off, 64);
  float scale = rsqrtf(ss*(1.f/128.f) + 1.1920929e-07f);
  xp[lane]    = f2bf(o1*scale);
  xp[lane+64] = f2bf(o2*scale);
}

// ---------------- windowed gated attention ----------------
// grid (T/64, B*H), 256 thr (4 waves, 16 q-rows each). K-tiles of 32.
__global__ __launch_bounds__(256) void attn_kernel(const unsigned short* __restrict__ Qh,
    const unsigned short* __restrict__ Kh, const unsigned short* __restrict__ Vh,
    const float* __restrict__ cumF, unsigned short* __restrict__ Y,
    const int* __restrict__ winp){
  __shared__ unsigned short smem[8192];     // Ks[32][128] | Vt[128][32], reused as Ys[64][128]
  unsigned short* Ks = smem;
  unsigned short* Vt = smem + 4096;
  const int q0b = blockIdx.x*64;
  const int bh = blockIdx.y;
  const int b = bh >> 4, h = bh & 15;
  const int tid = threadIdx.x, lane = tid & 63, wv = tid >> 6;
  const int g = lane >> 4, qi = lane & 15;
  const int win = *winp;
  const unsigned short* Qp = Qh + (size_t)bh*T_SEQ*DHEAD;
  const unsigned short* Kp = Kh + (size_t)bh*T_SEQ*DHEAD;
  const unsigned short* Vp = Vh + (size_t)bh*T_SEQ*DHEAD;
  const float* cF = cumF + (size_t)bh*T_SEQ;
  const int q0w = q0b + wv*16;
  const int qg = q0w + qi;
  const float cFq = cF[qg];
  bf16x8_t qf[4];
  #pragma unroll
  for (int dt=0;dt<4;dt++)
    qf[dt] = *reinterpret_cast<const bf16x8_t*>(Qp + (size_t)qg*DHEAD + dt*32 + g*8);
  f32x4_t ot[8] = {};
  float mrun = -1e30f, lrun = 0.f;
  const float sm_scale = 0.08838834764831845f;  // 1/sqrt(128)
  int kbeg = q0b - win + 1; if (kbeg < 0) kbeg = 0; kbeg &= ~31;
  const int kend = q0b + 64;
  for (int k0 = kbeg; k0 < kend; k0 += 32){
    __syncthreads();
    // stage K (XOR-swizzled rows) and V transposed
    #pragma unroll
    for (int i=0;i<2;i++){
      int ci = i*256 + tid;
      int row = ci >> 4, cc = ci & 15;
      u16x8_t kv = *reinterpret_cast<const u16x8_t*>(Kp + (size_t)(k0+row)*DHEAD + cc*8);
      *reinterpret_cast<u16x8_t*>(Ks + row*128 + ((cc ^ (row & 7))*8)) = kv;
      u16x8_t vv = *reinterpret_cast<const u16x8_t*>(Vp + (size_t)(k0+row)*DHEAD + cc*8);
      #pragma unroll
      for (int e=0;e<8;e++){
        int d = cc*8 + e;
        Vt[d*32 + (((row>>3) ^ (d&3))*8) + (row & 7)] = vv[e];
      }
    }
    __syncthreads();
    if (k0 <= q0w + 15 && k0 + 31 >= q0w - win + 1){
      // S^T = K * Q : col = query, row = key
      f32x4_t s0 = {}, s1 = {};
      #pragma unroll
      for (int dt=0;dt<4;dt++){
        int ch = dt*4 + g;
        int r0 = qi, r1 = 16 + qi;
        bf16x8_t k0f = *reinterpret_cast<const bf16x8_t*>(Ks + r0*128 + ((ch ^ (r0&7))*8));
        bf16x8_t k1f = *reinterpret_cast<const bf16x8_t*>(Ks + r1*128 + ((ch ^ (r1&7))*8));
        s0 = __builtin_amdgcn_mfma_f32_16x16x32_bf16(k0f, qf[dt], s0, 0, 0, 0);
        s1 = __builtin_amdgcn_mfma_f32_16x16x32_bf16(k1f, qf[dt], s1, 0, 0, 0);
      }
      float4 ca = *(const float4*)(cF + k0 + 4*g);
      float4 cb = *(const float4*)(cF + k0 + 16 + 4*g);
      float p0[4], p1[4];
      float tmax = -INFINITY;
      #pragma unroll
      for (int r=0;r<4;r++){
        int kg0 = k0 + 4*g + r;
        float sv = fmaf(s0[r], sm_scale, cFq - ((const float*)&ca)[r]);
        p0[r] = (kg0 <= qg && qg - kg0 < win) ? sv : -INFINITY;
        tmax = fmaxf(tmax, p0[r]);
        int kg1 = kg0 + 16;
        sv = fmaf(s1[r], sm_scale, cFq - ((const float*)&cb)[r]);
        p1[r] = (kg1 <= qg && qg - kg1 < win) ? sv : -INFINITY;
        tmax = fmaxf(tmax, p1[r]);
      }
      tmax = fmaxf(tmax, __shfl_xor(tmax, 16, 64));
      tmax = fmaxf(tmax, __shfl_xor(tmax, 32, 64));
      float mnew = fmaxf(mrun, tmax);
      float alpha = __expf(mrun - mnew);
      float tsum = 0.f;
      #pragma unroll
      for (int r=0;r<4;r++){
        p0[r] = __expf(p0[r] - mnew);
        p1[r] = __expf(p1[r] - mnew);
        tsum += p0[r] + p1[r];
      }
      tsum += __shfl_xor(tsum, 16, 64);
      tsum += __shfl_xor(tsum, 32, 64);
      lrun = lrun*alpha + tsum;
      mrun = mnew;
      #pragma unroll
      for (int dt=0;dt<8;dt++) ot[dt] *= alpha;
      // redistribute P (C-layout) into PV B-fragment via shfl
      u16x8_t pu;
      #pragma unroll
      for (int j=0;j<8;j++){
        int src = (2*(g&1) + (j>>2))*16 + qi;
        float v0 = __shfl(p0[j&3], src, 64);
        float v1 = __shfl(p1[j&3], src, 64);
        pu[j] = f2bf((g >= 2) ? v1 : v0);
      }
      bf16x8_t pb = *reinterpret_cast<bf16x8_t*>(&pu);
      // O^T += V^T * P^T
      #pragma unroll
      for (int dt=0;dt<8;dt++){
        int d = dt*16 + qi;
        bf16x8_t vf = *reinterpret_cast<const bf16x8_t*>(Vt + d*32 + ((g ^ (d&3))*8));
        ot[dt] = __builtin_amdgcn_mfma_f32_16x16x32_bf16(vf, pb, ot[dt], 0, 0, 0);
      }
    }
  }
  __syncthreads();
  float invl = 1.0f / lrun;
  #pragma unroll
  for (int dt=0;dt<8;dt++){
    #pragma unroll
    for (int r=0;r<4;r++)
      smem[(wv*16 + qi)*128 + dt*16 + 4*g + r] = f2bf(ot[dt][r]*invl);
  }
  __syncthreads();
  #pragma unroll
  for (int i=0;i<4;i++){
    int ci = i*256 + tid;
    int row = ci >> 4, cc = ci & 15;
    u16x8_t v = *reinterpret_cast<const u16x8_t*>(smem + row*128 + cc*8);
    *reinterpret_cast<u16x8_t*>(Y + ((size_t)b*T_SEQ + q0b + row)*CDIM + h*DHEAD + cc*8) = v;
  }
}

extern "C" void kernel_launch(void* const* d_in, const int* in_sizes, int n_in,
                              void* d_out, int out_size, void* d_ws, size_t ws_size,
                              hipStream_t stream){
  const float* x    = (const float*)d_in[0];
  const float* cosT = (const float*)d_in[1];
  const float* sinT = (const float*)d_in[2];
  const float* Wq   = (const float*)d_in[3];
  const float* Wk   = (const float*)d_in[4];
  const float* Wv   = (const float*)d_in[5];
  const float* Wo   = (const float*)d_in[6];
  const float* fgw  = (const float*)d_in[7];
  const float* fgb  = (const float*)d_in[8];
  const float* wlam = (const float*)d_in[9];
  const int*   winp = (const int*)d_in[10];

  char* ws = (char*)d_ws;
  // byte offsets (total ~112.5 MB)
  unsigned short* xb  = (unsigned short*)(ws + 0);          // 16 MB  [4096][2048] bf16
  unsigned short* WqT = (unsigned short*)(ws + 16777216);   // 8 MB   [2048][2048] bf16 (N,K)
  unsigned short* WkT = (unsigned short*)(ws + 25165824);
  unsigned short* WvT = (unsigned short*)(ws + 33554432);
  unsigned short* WoT = (unsigned short*)(ws + 41943040);
  unsigned short* Qh  = (unsigned short*)(ws + 50331648);   // 16 MB (B,H,T,D) bf16
  unsigned short* Kh  = (unsigned short*)(ws + 67108864);
  unsigned short* Vh  = (unsigned short*)(ws + 83886080);
  unsigned short* Yb  = (unsigned short*)(ws + 100663296);  // 16 MB [4096][2048] bf16
  float* lfg  = (float*)(ws + 117440512);                   // 256 KB [B*H][T]
  float* cumF = (float*)(ws + 117702656);                   // 256 KB [B*H][T]

  cast_f32_bf16<<<4096, 256, 0, stream>>>(x, xb, BT*CDIM);
  dim3 tgrid(64,64), tblk(32,8);
  transpose_cast<<<tgrid, tblk, 0, stream>>>(Wq, WqT);
  transpose_cast<<<tgrid, tblk, 0, stream>>>(Wk, WkT);
  transpose_cast<<<tgrid, tblk, 0, stream>>>(Wv, WvT);
  transpose_cast<<<tgrid, tblk, 0, stream>>>(Wo, WoT);

  dim3 ggrid(CDIM/128, BT/128);  // (16, 32)
  gemm_bt<1><<<ggrid, 256, 0, stream>>>(xb, WqT, Qh, BT, CDIM, CDIM);
  gemm_bt<1><<<ggrid, 256, 0, stream>>>(xb, WkT, Kh, BT, CDIM, CDIM);
  gemm_bt<1><<<ggrid, 256, 0, stream>>>(xb, WvT, Vh, BT, CDIM, CDIM);

  gates_kernel<<<BT, 256, 0, stream>>>(x, fgw, fgb, wlam, lfg);
  cumsum_kernel<<<BHT, 256, 0, stream>>>(lfg, cumF);

  rope_rms<<<BHT*T_SEQ/4, 256, 0, stream>>>(Qh, cosT, sinT);
  rope_rms<<<BHT*T_SEQ/4, 256, 0, stream>>>(Kh, cosT, sinT);

  attn_kernel<<<dim3(T_SEQ/64, BHT), 256, 0, stream>>>(Qh, Kh, Vh, cumF, Yb, winp);

  gemm_bt<2><<<ggrid, 256, 0, stream>>>(Yb, WoT, d_out, BT, CDIM, CDIM);
}

// Round 2
// 398.034 us; speedup vs baseline: 1.4866x; 1.4866x over previous
//
#include <hip/hip_runtime.h>
#include <hip/hip_bf16.h>
#include <stdint.h>

#define T_SEQ 2048
#define CDIM  2048
#define NHEAD 16
#define DHEAD 128
#define BT    4096   // B*T
#define BHT   32     // B*H
#define NQKV  6144

typedef __bf16 bf16x8_t __attribute__((ext_vector_type(8)));
typedef float  f32x4_t  __attribute__((ext_vector_type(4)));
typedef unsigned short u16x8_t __attribute__((ext_vector_type(8)));
typedef unsigned short u16x4_t __attribute__((ext_vector_type(4)));

__device__ __forceinline__ unsigned short f2bf(float f){
  unsigned int u = __float_as_uint(f);
  u += 0x7fffu + ((u >> 16) & 1u);
  return (unsigned short)(u >> 16);
}
__device__ __forceinline__ float bf2f(unsigned short h){
  return __uint_as_float(((unsigned int)h) << 16);
}
__device__ __forceinline__ unsigned ldsaddr(const void* p){
  return (unsigned)(size_t)(const __attribute__((address_space(3))) void*)p;
}
__device__ __forceinline__ u16x4_t tr16(unsigned a){
  u16x4_t r;
  asm volatile("ds_read_b64_tr_b16 %0, %1" : "=v"(r) : "v"(a));
  return r;
}

// ---------------- cast x (f32 -> bf16) ----------------
__global__ __launch_bounds__(256) void cast_f32_bf16(const float* __restrict__ in,
                                                     unsigned short* __restrict__ out, int n){
  int i = (blockIdx.x*256 + threadIdx.x)*8;
  if (i >= n) return;
  float4 a = *(const float4*)(in + i);
  float4 b = *(const float4*)(in + i + 4);
  u16x8_t o;
  o[0]=f2bf(a.x); o[1]=f2bf(a.y); o[2]=f2bf(a.z); o[3]=f2bf(a.w);
  o[4]=f2bf(b.x); o[5]=f2bf(b.y); o[6]=f2bf(b.z); o[7]=f2bf(b.w);
  *(u16x8_t*)(out + i) = o;
}

// ---------------- transpose + cast W (f32 [K][N] -> bf16 [N][K]) ----------------
__global__ __launch_bounds__(256) void transpose_cast(const float* __restrict__ W,
                                                      unsigned short* __restrict__ Wt){
  __shared__ float tile[32][33];
  int n0 = blockIdx.x*32, k0 = blockIdx.y*32;
  int tx = threadIdx.x, ty = threadIdx.y;  // 32 x 8
  #pragma unroll
  for (int i=0;i<32;i+=8)
    tile[ty+i][tx] = W[(size_t)(k0+ty+i)*CDIM + n0 + tx];
  __syncthreads();
  #pragma unroll
  for (int i=0;i<32;i+=8)
    Wt[(size_t)(n0+ty+i)*CDIM + k0 + tx] = f2bf(tile[tx][ty+i]);
}

// ---------------- bf16 MFMA GEMM: C[M][N] = A[M][K] * Bt[N][K]^T ----------------
// MODE 1: bf16 scatter to 3x(B,H,T,D) for fused QKV; MODE 2: f32 plain
template<int MODE>
__global__ __launch_bounds__(256) void gemm_bt(const unsigned short* __restrict__ A,
                                               const unsigned short* __restrict__ Bt,
                                               void* __restrict__ Cout,
                                               int M, int N, int K){
  __shared__ unsigned short As[128*32];
  __shared__ unsigned short Bs[128*32];
  // XCD-aware swizzle (T1): nwg % 8 == 0 guaranteed by launch config
  const int nx = gridDim.x;
  const int nwg = nx * gridDim.y;
  const int d0 = blockIdx.y*nx + blockIdx.x;
  const int wg = (d0 & 7)*(nwg >> 3) + (d0 >> 3);
  const int m0 = (wg / nx)*128, n0 = (wg % nx)*128;
  const int tid = threadIdx.x;
  const int lane = tid & 63, wv = tid >> 6;
  const int g = lane >> 4, qi = lane & 15;
  const int wm = (wv >> 1)*64, wn = (wv & 1)*64;
  f32x4_t acc[4][4] = {};
  for (int k0 = 0; k0 < K; k0 += 32){
    __syncthreads();
    #pragma unroll
    for (int i=0;i<2;i++){
      int ci = i*256 + tid;
      int row = ci >> 2, kc = ci & 3;
      __builtin_amdgcn_global_load_lds(
        (const __attribute__((address_space(1))) void*)(A + (size_t)(m0+row)*K + k0 + kc*8),
        (__attribute__((address_space(3))) void*)(As + ci*8), 16, 0, 0);
      __builtin_amdgcn_global_load_lds(
        (const __attribute__((address_space(1))) void*)(Bt + (size_t)(n0+row)*K + k0 + kc*8),
        (__attribute__((address_space(3))) void*)(Bs + ci*8), 16, 0, 0);
    }
    __syncthreads();
    bf16x8_t af[4], bfr[4];
    #pragma unroll
    for (int mi=0;mi<4;mi++)
      af[mi] = *reinterpret_cast<const bf16x8_t*>(As + (wm + mi*16 + qi)*32 + g*8);
    #pragma unroll
    for (int ni=0;ni<4;ni++)
      bfr[ni] = *reinterpret_cast<const bf16x8_t*>(Bs + (wn + ni*16 + qi)*32 + g*8);
    #pragma unroll
    for (int mi=0;mi<4;mi++){
      #pragma unroll
      for (int ni=0;ni<4;ni++){
        acc[mi][ni] = __builtin_amdgcn_mfma_f32_16x16x32_bf16(af[mi], bfr[ni], acc[mi][ni], 0, 0, 0);
      }
    }
  }
  #pragma unroll
  for (int mi=0;mi<4;mi++){
    #pragma unroll
    for (int ni=0;ni<4;ni++){
      #pragma unroll
      for (int r=0;r<4;r++){
        int mm = m0 + wm + mi*16 + 4*g + r;
        int nn = n0 + wn + ni*16 + qi;
        float v = acc[mi][ni][r];
        if (MODE == 2){
          ((float*)Cout)[(size_t)mm*N + nn] = v;
        } else {
          int b = mm >> 11, t = mm & (T_SEQ-1);
          int which = nn >> 11;             // 0=Q 1=K 2=V
          int hh = (nn >> 7) & 15, d = nn & (DHEAD-1);
          ((unsigned short*)Cout)[(size_t)which*8388608 +
              (((size_t)b*NHEAD + hh)*T_SEQ + t)*DHEAD + d] = f2bf(v);
        }
      }
    }
  }
}

// ---------------- gates: lam/logit/log_fgate per (b,t,h) ----------------
__global__ __launch_bounds__(256) void gates_kernel(const float* __restrict__ x,
    const float* __restrict__ fgw, const float* __restrict__ fgb,
    const float* __restrict__ wlam, float* __restrict__ lfg){
  __shared__ float xs[2048];
  __shared__ float part[256];
  const int row = blockIdx.x;     // b*T + t
  const int tid = threadIdx.x;
  const float* xp = x + (size_t)row*CDIM;
  #pragma unroll
  for (int i=0;i<2;i++)
    *(float4*)(xs + (i*256+tid)*4) = *(const float4*)(xp + (i*256+tid)*4);
  __syncthreads();
  const int col = tid & 31;       // 0-15: fgate, 16-31: lambda
  const int seg = tid >> 5;       // 0..7
  const float* W = (col < 16) ? fgw : wlam;
  const int h = col & 15;
  float acc = 0.f;
  for (int k = seg*256; k < seg*256 + 256; ++k)
    acc = fmaf(xs[k], W[k*16 + h], acc);
  part[tid] = acc;
  __syncthreads();
  for (int s=4; s>=1; s>>=1){
    if (seg < s) part[tid] += part[tid + s*32];
    __syncthreads();
  }
  if (tid < 16){
    float df = part[tid];
    float dl = part[16 + tid];
    float lam = (dl > 0.f) ? (dl + 1.f) : __expf(dl);   // elu + 1
    float logit = (df + fgb[tid]) * lam;
    float ls = fminf(logit, 0.f) - log1pf(__expf(-fabsf(logit))); // log_sigmoid
    float lf = ls / (lam + 0.001f);
    int b = row >> 11, t = row & (T_SEQ-1);
    lfg[((size_t)b*NHEAD + tid)*T_SEQ + t] = lf;
  }
}

// ---------------- inclusive cumsum along T per (b,h) ----------------
__global__ __launch_bounds__(256) void cumsum_kernel(const float* __restrict__ lfg,
                                                     float* __restrict__ cumF){
  __shared__ float sums[256];
  const int bh = blockIdx.x;
  const float* in = lfg + (size_t)bh*T_SEQ;
  float* out = cumF + (size_t)bh*T_SEQ;
  const int tid = threadIdx.x;
  float4 a = *(const float4*)(in + tid*8);
  float4 b = *(const float4*)(in + tid*8 + 4);
  float v[8] = {a.x,a.y,a.z,a.w,b.x,b.y,b.z,b.w};
  float run = 0.f;
  #pragma unroll
  for (int e=0;e<8;e++) run += v[e];
  sums[tid] = run;
  __syncthreads();
  for (int off=1; off<256; off<<=1){
    float y = (tid >= off) ? sums[tid-off] : 0.f;
    __syncthreads();
    sums[tid] += y;
    __syncthreads();
  }
  float acc = sums[tid] - run;  // exclusive prefix
  float o[8];
  #pragma unroll
  for (int e=0;e<8;e++){ acc += v[e]; o[e] = acc; }
  *(float4*)(out + tid*8)     = make_float4(o[0],o[1],o[2],o[3]);
  *(float4*)(out + tid*8 + 4) = make_float4(o[4],o[5],o[6],o[7]);
}

// ---------------- in-place RoPE + RMSNorm on (B*H, T, D) bf16 ----------------
__global__ __launch_bounds__(256) void rope_rms(unsigned short* __restrict__ X,
    const float* __restrict__ cosT, const float* __restrict__ sinT){
  const int tid = threadIdx.x, lane = tid & 63, wv = tid >> 6;
  const int idx = blockIdx.x*4 + wv;        // (b*H + h)*T + t
  const int t = idx & (T_SEQ-1);
  unsigned short* xp = X + (size_t)idx*DHEAD;
  float x1 = bf2f(xp[lane]);
  float x2 = bf2f(xp[lane+64]);
  float c = cosT[t*64 + lane];
  float s = sinT[t*64 + lane];
  float o1 = x1*c + x2*s;
  float o2 = x2*c - x1*s;
  float ss = o1*o1 + o2*o2;
  #pragma unroll
  for (int off=1; off<64; off<<=1) ss += __shfl_xor(ss, off, 64);
  float scale = rsqrtf(ss*(1.f/128.f) + 1.1920929e-07f);
  xp[lane]    = f2bf(o1*scale);
  xp[lane+64] = f2bf(o2*scale);
}

// ---------------- windowed gated attention ----------------
// grid (16, 32) -> XCD-swizzled to (qtile, bh); 256 thr = 4 waves x 32 queries.
// KVBLK=64 double-buffered: K linear+XOR-swz [64][128], V subtiled [8][16][4][16] for tr16.
__global__ __launch_bounds__(256, 2) void attn_kernel(const unsigned short* __restrict__ Qh,
    const unsigned short* __restrict__ Kh, const unsigned short* __restrict__ Vh,
    const float* __restrict__ cumF, unsigned short* __restrict__ Y,
    const int* __restrict__ winp){
  __shared__ unsigned short smem[32768];     // 64 KB: K0|K1|V0|V1 (8192 elems each)
  // XCD swizzle: all 16 q-tiles of head bh land on XCD bh%8
  const int dlin = blockIdx.y*16 + blockIdx.x;
  const int c8 = dlin & 7, klin = dlin >> 3;
  const int bh = c8 + 8*(klin >> 4);
  const int q0b = (klin & 15)*128;
  const int b = bh >> 4, h = bh & 15;
  const int tid = threadIdx.x, lane = tid & 63, wv = tid >> 6;
  const int g = lane >> 4, qi = lane & 15;
  const int win = *winp;
  const unsigned short* Qp = Qh + (size_t)bh*T_SEQ*DHEAD;
  const unsigned short* Kp = Kh + (size_t)bh*T_SEQ*DHEAD;
  const unsigned short* Vp = Vh + (size_t)bh*T_SEQ*DHEAD;
  const float* cF = cumF + (size_t)bh*T_SEQ;
  const int q0w = q0b + wv*32;
  bf16x8_t qf[2][4];
  float cFq[2];
  #pragma unroll
  for (int qb=0;qb<2;qb++){
    cFq[qb] = cF[q0w + qb*16 + qi];
    #pragma unroll
    for (int dt=0;dt<4;dt++)
      qf[qb][dt] = *reinterpret_cast<const bf16x8_t*>(Qp + (size_t)(q0w + qb*16 + qi)*DHEAD + dt*32 + g*8);
  }
  f32x4_t ot[2][8] = {};
  float mrun[2] = {-1e30f, -1e30f}, lrun[2] = {0.f, 0.f};
  const float sm_scale = 0.08838834764831845f;  // 1/sqrt(128)
  int kbeg = q0b - win + 1; if (kbeg < 0) kbeg = 0; kbeg &= ~63;
  const int nt = (q0b + 128 - kbeg) >> 6;

  auto stage = [&](int bi, int k0s){
    unsigned short* Kd = smem + bi*8192;
    unsigned short* Vd = smem + 16384 + bi*8192;
    #pragma unroll
    for (int jj=0;jj<4;jj++){
      int t = (wv*4+jj)*64 + lane;
      int r = t>>4, cc = t&15;
      // K: linear dest, inverse-XOR-swizzled global source (rule 21)
      __builtin_amdgcn_global_load_lds(
        (const __attribute__((address_space(1))) void*)(Kp + (size_t)(k0s+r)*DHEAD + ((cc ^ (r&7))*8)),
        (__attribute__((address_space(3))) void*)(Kd + t*8), 16, 0, 0);
      // V: subtiled [dd][kk][4][16], dd-major; slot t -> (dd,kk,rr,hb)
      int dd = t>>7, kq = (t>>3)&15, rr = (t>>1)&3, hb = t&1;
      __builtin_amdgcn_global_load_lds(
        (const __attribute__((address_space(1))) void*)(Vp + (size_t)(k0s + kq*4 + rr)*DHEAD + dd*16 + hb*8),
        (__attribute__((address_space(3))) void*)(Vd + t*8), 16, 0, 0);
    }
  };

  stage(0, kbeg);
  for (int it=0; it<nt; ++it){
    const int k0 = kbeg + it*64;
    const int cur = it & 1;
    __syncthreads();   // vmcnt(0) drain completes buf[cur]; also protects buf[cur^1] overwrite
    if (it+1 < nt) stage(cur^1, k0+64);
    if (k0 <= q0w+31 && (k0 + 63) >= (q0w - win + 1)){
      const unsigned short* Kc = smem + cur*8192;
      // S^T = K * Q  (A = K rows natural, B = Q rows natural)
      f32x4_t s[2][4] = {};
      __builtin_amdgcn_s_setprio(1);
      #pragma unroll
      for (int dt=0;dt<4;dt++){
        bf16x8_t kf[4];
        #pragma unroll
        for (int kb=0;kb<4;kb++){
          int row = kb*16 + qi;
          kf[kb] = *reinterpret_cast<const bf16x8_t*>(Kc + row*128 + (((dt*4+g) ^ (row&7))*8));
        }
        #pragma unroll
        for (int kb=0;kb<4;kb++){
          s[0][kb] = __builtin_amdgcn_mfma_f32_16x16x32_bf16(kf[kb], qf[0][dt], s[0][kb], 0,0,0);
          s[1][kb] = __builtin_amdgcn_mfma_f32_16x16x32_bf16(kf[kb], qf[1][dt], s[1][kb], 0,0,0);
        }
      }
      __builtin_amdgcn_s_setprio(0);
      float4 cb[4];
      #pragma unroll
      for (int kb=0;kb<4;kb++) cb[kb] = *(const float4*)(cF + k0 + kb*16 + 4*g);
      u16x8_t pb[2][2];
      #pragma unroll
      for (int qb=0;qb<2;qb++){
        const int qg = q0w + qb*16 + qi;
        float p[16], tmax = -INFINITY;
        #pragma unroll
        for (int kb=0;kb<4;kb++){
          #pragma unroll
          for (int r=0;r<4;r++){
            int key = k0 + kb*16 + 4*g + r;
            float sv = fmaf(s[qb][kb][r], sm_scale, cFq[qb] - ((const float*)&cb[kb])[r]);
            bool ok = (key <= qg) && (qg - key < win);
            p[kb*4+r] = ok ? sv : -INFINITY;
            tmax = fmaxf(tmax, p[kb*4+r]);
          }
        }
        tmax = fmaxf(tmax, __shfl_xor(tmax, 16, 64));
        tmax = fmaxf(tmax, __shfl_xor(tmax, 32, 64));
        float mnew = fmaxf(mrun[qb], tmax);
        float alpha = __expf(mrun[qb] - mnew);
        float tsum = 0.f;
        #pragma unroll
        for (int i2=0;i2<16;i2++){ p[i2] = __expf(p[i2] - mnew); tsum += p[i2]; }
        tsum += __shfl_xor(tsum, 16, 64);
        tsum += __shfl_xor(tsum, 32, 64);
        lrun[qb] = lrun[qb]*alpha + tsum;
        mrun[qb] = mnew;
        #pragma unroll
        for (int dt=0;dt<8;dt++) ot[qb][dt] *= alpha;
        // B-frag slot e of chunk cc: key = 32cc + 16*(e>=4) + 4g + (e&3)  == p[(2cc+(e>>2))*4 + (e&3)]
        #pragma unroll
        for (int cc=0;cc<2;cc++){
          #pragma unroll
          for (int e=0;e<8;e++)
            pb[qb][cc][e] = f2bf(p[(2*cc + (e>>2))*4 + (e&3)]);
        }
      }
      // O^T += V^T * P^T ; V^T fragments via hardware transpose-read
      unsigned vbase = ldsaddr(smem + 16384 + cur*8192) + lane*8;
      #pragma unroll
      for (int cc=0;cc<2;cc++){
        u16x4_t vlo[8], vhi[8];
        #pragma unroll
        for (int dt=0;dt<8;dt++){
          vlo[dt] = tr16(vbase + (unsigned)((dt*16 + 8*cc)*128));
          vhi[dt] = tr16(vbase + (unsigned)((dt*16 + 8*cc + 4)*128));
        }
        asm volatile("s_waitcnt lgkmcnt(0)");
        __builtin_amdgcn_sched_barrier(0);
        __builtin_amdgcn_s_setprio(1);
        #pragma unroll
        for (int dt=0;dt<8;dt++){
          u16x8_t vv = __builtin_shufflevector(vlo[dt], vhi[dt], 0,1,2,3,4,5,6,7);
          bf16x8_t vf = *reinterpret_cast<bf16x8_t*>(&vv);
          ot[0][dt] = __builtin_amdgcn_mfma_f32_16x16x32_bf16(vf, *reinterpret_cast<bf16x8_t*>(&pb[0][cc]), ot[0][dt], 0,0,0);
          ot[1][dt] = __builtin_amdgcn_mfma_f32_16x16x32_bf16(vf, *reinterpret_cast<bf16x8_t*>(&pb[1][cc]), ot[1][dt], 0,0,0);
        }
        __builtin_amdgcn_s_setprio(0);
      }
    }
  }
  __syncthreads();
  // epilogue: normalize, stage O[128][128] in LDS (XOR-swizzled), coalesced store
  float invl[2] = {1.f/lrun[0], 1.f/lrun[1]};
  #pragma unroll
  for (int qb=0;qb<2;qb++){
    int qlocal = wv*32 + qb*16 + qi;
    #pragma unroll
    for (int dt=0;dt<8;dt++){
      int d8 = dt*2 + (g>>1);
      u16x4_t w;
      #pragma unroll
      for (int r=0;r<4;r++) w[r] = f2bf(ot[qb][dt][r]*invl[qb]);
      *reinterpret_cast<u16x4_t*>(smem + qlocal*128 + ((d8 ^ (qlocal&7))*8) + 4*(g&1)) = w;
    }
  }
  __syncthreads();
  #pragma unroll
  for (int i=0;i<8;i++){
    int t = i*256 + tid;
    int row = t>>4, cc = t&15;
    u16x8_t v = *reinterpret_cast<const u16x8_t*>(smem + row*128 + ((cc ^ (row&7))*8));
    *reinterpret_cast<u16x8_t*>(Y + ((size_t)b*T_SEQ + q0b + row)*CDIM + h*DHEAD + cc*8) = v;
  }
}

extern "C" void kernel_launch(void* const* d_in, const int* in_sizes, int n_in,
                              void* d_out, int out_size, void* d_ws, size_t ws_size,
                              hipStream_t stream){
  const float* x    = (const float*)d_in[0];
  const float* cosT = (const float*)d_in[1];
  const float* sinT = (const float*)d_in[2];
  const float* Wq   = (const float*)d_in[3];
  const float* Wk   = (const float*)d_in[4];
  const float* Wv   = (const float*)d_in[5];
  const float* Wo   = (const float*)d_in[6];
  const float* fgw  = (const float*)d_in[7];
  const float* fgb  = (const float*)d_in[8];
  const float* wlam = (const float*)d_in[9];
  const int*   winp = (const int*)d_in[10];

  char* ws = (char*)d_ws;
  unsigned short* xb    = (unsigned short*)(ws + 0);          // 16 MB  [4096][2048] bf16
  unsigned short* WqkvT = (unsigned short*)(ws + 16777216);   // 24 MB  [6144][2048] bf16 (N,K)
  unsigned short* WoT   = (unsigned short*)(ws + 41943040);   // 8 MB
  unsigned short* QKVh  = (unsigned short*)(ws + 50331648);   // 48 MB: Q|K|V each (B,H,T,D)
  unsigned short* Qh = QKVh;
  unsigned short* Kh = QKVh + 8388608;
  unsigned short* Vh = QKVh + 16777216;
  unsigned short* Yb  = (unsigned short*)(ws + 100663296);    // 16 MB [4096][2048] bf16
  float* lfg  = (float*)(ws + 117440512);                     // 256 KB [B*H][T]
  float* cumF = (float*)(ws + 117702656);                     // 256 KB [B*H][T]

  cast_f32_bf16<<<4096, 256, 0, stream>>>(x, xb, BT*CDIM);
  dim3 tgrid(64,64), tblk(32,8);
  transpose_cast<<<tgrid, tblk, 0, stream>>>(Wq, WqkvT);
  transpose_cast<<<tgrid, tblk, 0, stream>>>(Wk, WqkvT + 4194304);
  transpose_cast<<<tgrid, tblk, 0, stream>>>(Wv, WqkvT + 8388608);
  transpose_cast<<<tgrid, tblk, 0, stream>>>(Wo, WoT);

  gemm_bt<1><<<dim3(NQKV/128, BT/128), 256, 0, stream>>>(xb, WqkvT, QKVh, BT, NQKV, CDIM);

  gates_kernel<<<BT, 256, 0, stream>>>(x, fgw, fgb, wlam, lfg);
  cumsum_kernel<<<BHT, 256, 0, stream>>>(lfg, cumF);

  rope_rms<<<BHT*T_SEQ/4, 256, 0, stream>>>(Qh, cosT, sinT);
  rope_rms<<<BHT*T_SEQ/4, 256, 0, stream>>>(Kh, cosT, sinT);

  attn_kernel<<<dim3(16, BHT), 256, 0, stream>>>(Qh, Kh, Vh, cumF, Yb, winp);

  gemm_bt<2><<<dim3(CDIM/128, BT/128), 256, 0, stream>>>(Yb, WoT, d_out, BT, CDIM, CDIM);
}

// Round 4
// 374.427 us; speedup vs baseline: 1.5804x; 1.0630x over previous
//
#include <hip/hip_runtime.h>
#include <hip/hip_bf16.h>
#include <stdint.h>

#define T_SEQ 2048
#define CDIM  2048
#define NHEAD 16
#define DHEAD 128
#define BT    4096   // B*T
#define BHT   32     // B*H
#define NQKV  6144

typedef __bf16 bf16x8_t __attribute__((ext_vector_type(8)));
typedef float  f32x4_t  __attribute__((ext_vector_type(4)));
typedef unsigned short u16x8_t __attribute__((ext_vector_type(8)));
typedef unsigned short u16x4_t __attribute__((ext_vector_type(4)));

__device__ __forceinline__ unsigned short f2bf(float f){
  unsigned int u = __float_as_uint(f);
  u += 0x7fffu + ((u >> 16) & 1u);
  return (unsigned short)(u >> 16);
}
__device__ __forceinline__ float bf2f(unsigned short h){
  return __uint_as_float(((unsigned int)h) << 16);
}
__device__ __forceinline__ unsigned ldsaddr(const void* p){
  return (unsigned)(size_t)(const __attribute__((address_space(3))) void*)p;
}
__device__ __forceinline__ u16x4_t tr16(unsigned a){
  u16x4_t r;
  asm volatile("ds_read_b64_tr_b16 %0, %1" : "=v"(r) : "v"(a));
  return r;
}

// ---------------- cast x (f32 -> bf16) ----------------
__global__ __launch_bounds__(256) void cast_f32_bf16(const float* __restrict__ in,
                                                     unsigned short* __restrict__ out, int n){
  int i = (blockIdx.x*256 + threadIdx.x)*8;
  if (i >= n) return;
  float4 a = *(const float4*)(in + i);
  float4 b = *(const float4*)(in + i + 4);
  u16x8_t o;
  o[0]=f2bf(a.x); o[1]=f2bf(a.y); o[2]=f2bf(a.z); o[3]=f2bf(a.w);
  o[4]=f2bf(b.x); o[5]=f2bf(b.y); o[6]=f2bf(b.z); o[7]=f2bf(b.w);
  *(u16x8_t*)(out + i) = o;
}

// ---------------- transpose + cast W (f32 [K][N] -> bf16 [N][K]) ----------------
__global__ __launch_bounds__(256) void transpose_cast(const float* __restrict__ W,
                                                      unsigned short* __restrict__ Wt){
  __shared__ float tile[32][33];
  int n0 = blockIdx.x*32, k0 = blockIdx.y*32;
  int tx = threadIdx.x, ty = threadIdx.y;  // 32 x 8
  #pragma unroll
  for (int i=0;i<32;i+=8)
    tile[ty+i][tx] = W[(size_t)(k0+ty+i)*CDIM + n0 + tx];
  __syncthreads();
  #pragma unroll
  for (int i=0;i<32;i+=8)
    Wt[(size_t)(n0+ty+i)*CDIM + k0 + tx] = f2bf(tile[tx][ty+i]);
}

// ================= 256x256 8-phase GEMM (T2+T3+T4+T5) =================
// C[M][N] = A[M][K] * Bt[N][K]^T.  MODE 1: bf16 scatter to 3x(B,H,T,D).
// 512 thr = 8 waves (2M x 4N), BK=64, 2 K-tiles/iter, dyn LDS 128 KiB.
// Buffer parity is FIXED: buf0 always holds the even K-tile (2it, staged
// ph2/ph3, drained by the PREVIOUS ph7 vmcnt(8)+barrier); buf1 always holds
// the odd K-tile (2it+1, staged ph6/ph7, drained by THIS iter's ph3 vmcnt(8)).
// LDS (u16 units): buf*32768 + {A0:0, A1:8192, B0:16384, B1:24576} + sr*8.
// Swizzle: 16B-granule gr at (row) holds global k-granule gr^(row&7).

#define MFMA_PHASE(MQ, NQ, BB) do{ \
  __builtin_amdgcn_s_setprio(1); \
  _Pragma("unroll") for (int c=0;c<2;c++) \
  _Pragma("unroll") for (int rg=0;rg<4;rg++) \
  _Pragma("unroll") for (int ng=0;ng<2;ng++) \
    acc[(MQ)*4+rg][(NQ)*2+ng] = __builtin_amdgcn_mfma_f32_16x16x32_bf16( \
        af[rg][c], BB[ng][c], acc[(MQ)*4+rg][(NQ)*2+ng], 0,0,0); \
  __builtin_amdgcn_s_setprio(0); }while(0)

#define PH_SYNC_BEGIN() do{ __builtin_amdgcn_sched_barrier(0); \
  __builtin_amdgcn_s_barrier(); \
  asm volatile("s_waitcnt lgkmcnt(0)" ::: "memory"); \
  __builtin_amdgcn_sched_barrier(0); }while(0)

#define PH_END() do{ __builtin_amdgcn_sched_barrier(0); \
  __builtin_amdgcn_s_barrier(); }while(0)

template<int MODE>
__global__ __launch_bounds__(512, 2) void gemm256(const unsigned short* __restrict__ A,
                                                  const unsigned short* __restrict__ Bt,
                                                  void* __restrict__ Cout,
                                                  int M, int N, int K){
  extern __shared__ unsigned short lds[];
  const int nx = N >> 8;
  const int nwg = (M >> 8) * nx;
  const int bid = blockIdx.x;
  const int wg = (bid & 7)*(nwg >> 3) + (bid >> 3);   // nwg % 8 == 0
  const int m0 = (wg / nx) << 8, n0 = (wg % nx) << 8;
  const int tid = threadIdx.x, lane = tid & 63, wv = tid >> 6;
  const int wm = wv >> 2, wn = wv & 3;
  const int g = lane >> 4, qi = lane & 15;
  const int ktmax = (K >> 6) - 1;

  f32x4_t acc[8][4] = {};
  bf16x8_t af[4][2], bf0[2][2], bf1[2][2];

  // staging precompute: 4 slots/thread per stage call (2 regions x 1024 slots)
  int goff[4], loff[4];
  #pragma unroll
  for (int j=0;j<4;j++){
    int s = j*512 + tid;
    int sr = s & 1023, reg = s >> 10;
    int row = sr >> 3;
    int gs = (sr & 7) ^ (row & 7);
    goff[j] = (reg*128 + row)*K + gs*8;
    loff[j] = reg*8192 + sr*8;
  }
  auto stageA = [&](int buf, int kt){
    #pragma unroll
    for (int j=0;j<4;j++){
      const unsigned short* src = A + (size_t)m0*K + goff[j] + kt*64;
      unsigned short* dst = lds + buf*32768 + loff[j];
      __builtin_amdgcn_global_load_lds((const __attribute__((address_space(1))) void*)src,
          (__attribute__((address_space(3))) void*)dst, 16, 0, 0);
    }
  };
  auto stageB = [&](int buf, int kt){
    #pragma unroll
    for (int j=0;j<4;j++){
      const unsigned short* src = Bt + (size_t)n0*K + goff[j] + kt*64;
      unsigned short* dst = lds + buf*32768 + 16384 + loff[j];
      __builtin_amdgcn_global_load_lds((const __attribute__((address_space(1))) void*)src,
          (__attribute__((address_space(3))) void*)dst, 16, 0, 0);
    }
  };
  auto readA = [&](int buf, int mq){
    const unsigned short* base = lds + buf*32768 + wm*8192;
    #pragma unroll
    for (int rg=0;rg<4;rg++)
      #pragma unroll
      for (int c=0;c<2;c++){
        int row = mq*64 + rg*16 + qi;
        af[rg][c] = *reinterpret_cast<const bf16x8_t*>(base + row*64 + (((c*4+g) ^ (qi&7))*8));
      }
  };
  auto readB = [&](int buf, int nq, bf16x8_t (&bb)[2][2]){
    const unsigned short* base = lds + buf*32768 + 16384 + (wn>>1)*8192;
    #pragma unroll
    for (int ng=0;ng<2;ng++)
      #pragma unroll
      for (int c=0;c<2;c++){
        int row = (wn&1)*64 + nq*32 + ng*16 + qi;
        bb[ng][c] = *reinterpret_cast<const bf16x8_t*>(base + row*64 + (((c*4+g) ^ (qi&7))*8));
      }
  };

  // prologue: tile0 -> buf0, tile1 -> buf1 (16 loads/thread); drain tile0
  stageB(0,0); stageA(0,0); stageB(1,1); stageA(1,1);
  asm volatile("s_waitcnt vmcnt(8)" ::: "memory");
  __builtin_amdgcn_sched_barrier(0);
  __builtin_amdgcn_s_barrier();

  const int niter = K >> 7;
  for (int it=0; it<niter; ++it){
    int kt2 = 2*it+2; if (kt2 > ktmax) kt2 = ktmax;
    int kt3 = 2*it+3; if (kt3 > ktmax) kt3 = ktmax;
    // ---- K-tile 2it (buf0; resident: prev ph7 vmcnt(8)+barrier) ----
    readA(0,0); readB(0,0,bf0);                 // ph0
    PH_SYNC_BEGIN(); MFMA_PHASE(0,0,bf0); PH_END();
    readB(0,1,bf1);                             // ph1
    PH_SYNC_BEGIN(); MFMA_PHASE(0,1,bf1); PH_END();
    readA(0,1); stageB(0,kt2);                  // ph2 (buf0 B region dead)
    PH_SYNC_BEGIN(); MFMA_PHASE(1,1,bf1); PH_END();
    stageA(0,kt2);                              // ph3 (buf0 A region dead after ph2)
    PH_SYNC_BEGIN(); MFMA_PHASE(1,0,bf0);
    asm volatile("s_waitcnt vmcnt(8)" ::: "memory");  // drain tile 2it+1 (buf1)
    PH_END();
    // ---- K-tile 2it+1 (buf1) ----
    readA(1,0); readB(1,0,bf0);                 // ph4
    PH_SYNC_BEGIN(); MFMA_PHASE(0,0,bf0); PH_END();
    readB(1,1,bf1);                             // ph5
    PH_SYNC_BEGIN(); MFMA_PHASE(0,1,bf1); PH_END();
    readA(1,1); stageB(1,kt3);                  // ph6
    PH_SYNC_BEGIN(); MFMA_PHASE(1,1,bf1); PH_END();
    stageA(1,kt3);                              // ph7
    PH_SYNC_BEGIN(); MFMA_PHASE(1,0,bf0);
    asm volatile("s_waitcnt vmcnt(8)" ::: "memory");  // drain tile 2it+2 (buf0)
    PH_END();
  }

  // epilogue: scatter C
  #pragma unroll
  for (int mi=0;mi<8;mi++){
    #pragma unroll
    for (int ni=0;ni<4;ni++){
      #pragma unroll
      for (int r=0;r<4;r++){
        int mm = m0 + wm*128 + mi*16 + 4*g + r;
        int nn = n0 + wn*64  + ni*16 + qi;
        float v = acc[mi][ni][r];
        if (MODE == 2){
          ((float*)Cout)[(size_t)mm*N + nn] = v;
        } else {
          int bb2 = mm >> 11, t = mm & (T_SEQ-1);
          int which = nn >> 11;             // 0=Q 1=K 2=V
          int hh = (nn >> 7) & 15, d = nn & (DHEAD-1);
          ((unsigned short*)Cout)[(size_t)which*8388608 +
              (((size_t)bb2*NHEAD + hh)*T_SEQ + t)*DHEAD + d] = f2bf(v);
        }
      }
    }
  }
}

// ---------------- bf16 MFMA GEMM 128^2 (m97 structure): C = A * Bt^T ----------------
// MODE 1: bf16 scatter to 3x(B,H,T,D) (fallback only); MODE 2: f32 plain
template<int MODE>
__global__ __launch_bounds__(256) void gemm_bt(const unsigned short* __restrict__ A,
                                               const unsigned short* __restrict__ Bt,
                                               void* __restrict__ Cout,
                                               int M, int N, int K){
  __shared__ unsigned short As[128*32];
  __shared__ unsigned short Bs[128*32];
  const int nx = gridDim.x;
  const int nwg = nx * gridDim.y;
  const int d0 = blockIdx.y*nx + blockIdx.x;
  const int wg = (d0 & 7)*(nwg >> 3) + (d0 >> 3);
  const int m0 = (wg / nx)*128, n0 = (wg % nx)*128;
  const int tid = threadIdx.x;
  const int lane = tid & 63, wv = tid >> 6;
  const int g = lane >> 4, qi = lane & 15;
  const int wm = (wv >> 1)*64, wn = (wv & 1)*64;
  f32x4_t acc[4][4] = {};
  for (int k0 = 0; k0 < K; k0 += 32){
    __syncthreads();
    #pragma unroll
    for (int i=0;i<2;i++){
      int ci = i*256 + tid;
      int row = ci >> 2, kc = ci & 3;
      __builtin_amdgcn_global_load_lds(
        (const __attribute__((address_space(1))) void*)(A + (size_t)(m0+row)*K + k0 + kc*8),
        (__attribute__((address_space(3))) void*)(As + ci*8), 16, 0, 0);
      __builtin_amdgcn_global_load_lds(
        (const __attribute__((address_space(1))) void*)(Bt + (size_t)(n0+row)*K + k0 + kc*8),
        (__attribute__((address_space(3))) void*)(Bs + ci*8), 16, 0, 0);
    }
    __syncthreads();
    bf16x8_t af[4], bfr[4];
    #pragma unroll
    for (int mi=0;mi<4;mi++)
      af[mi] = *reinterpret_cast<const bf16x8_t*>(As + (wm + mi*16 + qi)*32 + g*8);
    #pragma unroll
    for (int ni=0;ni<4;ni++)
      bfr[ni] = *reinterpret_cast<const bf16x8_t*>(Bs + (wn + ni*16 + qi)*32 + g*8);
    #pragma unroll
    for (int mi=0;mi<4;mi++){
      #pragma unroll
      for (int ni=0;ni<4;ni++){
        acc[mi][ni] = __builtin_amdgcn_mfma_f32_16x16x32_bf16(af[mi], bfr[ni], acc[mi][ni], 0, 0, 0);
      }
    }
  }
  #pragma unroll
  for (int mi=0;mi<4;mi++){
    #pragma unroll
    for (int ni=0;ni<4;ni++){
      #pragma unroll
      for (int r=0;r<4;r++){
        int mm = m0 + wm + mi*16 + 4*g + r;
        int nn = n0 + wn + ni*16 + qi;
        float v = acc[mi][ni][r];
        if (MODE == 2){
          ((float*)Cout)[(size_t)mm*N + nn] = v;
        } else {
          int b = mm >> 11, t = mm & (T_SEQ-1);
          int which = nn >> 11;
          int hh = (nn >> 7) & 15, d = nn & (DHEAD-1);
          ((unsigned short*)Cout)[(size_t)which*8388608 +
              (((size_t)b*NHEAD + hh)*T_SEQ + t)*DHEAD + d] = f2bf(v);
        }
      }
    }
  }
}

// ---------------- gates: lam/logit/log_fgate per (b,t,h) ----------------
__global__ __launch_bounds__(256) void gates_kernel(const float* __restrict__ x,
    const float* __restrict__ fgw, const float* __restrict__ fgb,
    const float* __restrict__ wlam, float* __restrict__ lfg){
  __shared__ float xs[2048];
  __shared__ float part[256];
  const int row = blockIdx.x;     // b*T + t
  const int tid = threadIdx.x;
  const float* xp = x + (size_t)row*CDIM;
  #pragma unroll
  for (int i=0;i<2;i++)
    *(float4*)(xs + (i*256+tid)*4) = *(const float4*)(xp + (i*256+tid)*4);
  __syncthreads();
  const int col = tid & 31;       // 0-15: fgate, 16-31: lambda
  const int seg = tid >> 5;       // 0..7
  const float* W = (col < 16) ? fgw : wlam;
  const int h = col & 15;
  float acc = 0.f;
  for (int k = seg*256; k < seg*256 + 256; ++k)
    acc = fmaf(xs[k], W[k*16 + h], acc);
  part[tid] = acc;
  __syncthreads();
  for (int s=4; s>=1; s>>=1){
    if (seg < s) part[tid] += part[tid + s*32];
    __syncthreads();
  }
  if (tid < 16){
    float df = part[tid];
    float dl = part[16 + tid];
    float lam = (dl > 0.f) ? (dl + 1.f) : __expf(dl);   // elu + 1
    float logit = (df + fgb[tid]) * lam;
    float ls = fminf(logit, 0.f) - log1pf(__expf(-fabsf(logit))); // log_sigmoid
    float lf = ls / (lam + 0.001f);
    int b = row >> 11, t = row & (T_SEQ-1);
    lfg[((size_t)b*NHEAD + tid)*T_SEQ + t] = lf;
  }
}

// ---------------- inclusive cumsum along T per (b,h) ----------------
__global__ __launch_bounds__(256) void cumsum_kernel(const float* __restrict__ lfg,
                                                     float* __restrict__ cumF){
  __shared__ float sums[256];
  const int bh = blockIdx.x;
  const float* in = lfg + (size_t)bh*T_SEQ;
  float* out = cumF + (size_t)bh*T_SEQ;
  const int tid = threadIdx.x;
  float4 a = *(const float4*)(in + tid*8);
  float4 b = *(const float4*)(in + tid*8 + 4);
  float v[8] = {a.x,a.y,a.z,a.w,b.x,b.y,b.z,b.w};
  float run = 0.f;
  #pragma unroll
  for (int e=0;e<8;e++) run += v[e];
  sums[tid] = run;
  __syncthreads();
  for (int off=1; off<256; off<<=1){
    float y = (tid >= off) ? sums[tid-off] : 0.f;
    __syncthreads();
    sums[tid] += y;
    __syncthreads();
  }
  float acc = sums[tid] - run;  // exclusive prefix
  float o[8];
  #pragma unroll
  for (int e=0;e<8;e++){ acc += v[e]; o[e] = acc; }
  *(float4*)(out + tid*8)     = make_float4(o[0],o[1],o[2],o[3]);
  *(float4*)(out + tid*8 + 4) = make_float4(o[4],o[5],o[6],o[7]);
}

// ---------------- in-place RoPE + RMSNorm on (B*H, T, D) bf16 ----------------
__global__ __launch_bounds__(256) void rope_rms(unsigned short* __restrict__ X,
    const float* __restrict__ cosT, const float* __restrict__ sinT){
  const int tid = threadIdx.x, lane = tid & 63, wv = tid >> 6;
  const int idx = blockIdx.x*4 + wv;        // (b*H + h)*T + t
  const int t = idx & (T_SEQ-1);
  unsigned short* xp = X + (size_t)idx*DHEAD;
  float x1 = bf2f(xp[lane]);
  float x2 = bf2f(xp[lane+64]);
  float c = cosT[t*64 + lane];
  float s = sinT[t*64 + lane];
  float o1 = x1*c + x2*s;
  float o2 = x2*c - x1*s;
  float ss = o1*o1 + o2*o2;
  #pragma unroll
  for (int off=1; off<64; off<<=1) ss += __shfl_xor(ss, off, 64);
  float scale = rsqrtf(ss*(1.f/128.f) + 1.1920929e-07f);
  xp[lane]    = f2bf(o1*scale);
  xp[lane+64] = f2bf(o2*scale);
}

// ---------------- windowed gated attention ----------------
// grid (16, 32) -> XCD-swizzled to (qtile, bh); 256 thr = 4 waves x 32 queries.
// KVBLK=64 double-buffered: K linear+XOR-swz [64][128], V subtiled [8][16][4][16] for tr16.
__global__ __launch_bounds__(256, 2) void attn_kernel(const unsigned short* __restrict__ Qh,
    const unsigned short* __restrict__ Kh, const unsigned short* __restrict__ Vh,
    const float* __restrict__ cumF, unsigned short* __restrict__ Y,
    const int* __restrict__ winp){
  __shared__ unsigned short smem[32768];     // 64 KB: K0|K1|V0|V1 (8192 elems each)
  const int dlin = blockIdx.y*16 + blockIdx.x;
  const int c8 = dlin & 7, klin = dlin >> 3;
  const int bh = c8 + 8*(klin >> 4);
  const int q0b = (klin & 15)*128;
  const int b = bh >> 4, h = bh & 15;
  const int tid = threadIdx.x, lane = tid & 63, wv = tid >> 6;
  const int g = lane >> 4, qi = lane & 15;
  const int win = *winp;
  const unsigned short* Qp = Qh + (size_t)bh*T_SEQ*DHEAD;
  const unsigned short* Kp = Kh + (size_t)bh*T_SEQ*DHEAD;
  const unsigned short* Vp = Vh + (size_t)bh*T_SEQ*DHEAD;
  const float* cF = cumF + (size_t)bh*T_SEQ;
  const int q0w = q0b + wv*32;
  bf16x8_t qf[2][4];
  float cFq[2];
  #pragma unroll
  for (int qb=0;qb<2;qb++){
    cFq[qb] = cF[q0w + qb*16 + qi];
    #pragma unroll
    for (int dt=0;dt<4;dt++)
      qf[qb][dt] = *reinterpret_cast<const bf16x8_t*>(Qp + (size_t)(q0w + qb*16 + qi)*DHEAD + dt*32 + g*8);
  }
  f32x4_t ot[2][8] = {};
  float mrun[2] = {-1e30f, -1e30f}, lrun[2] = {0.f, 0.f};
  const float sm_scale = 0.08838834764831845f;  // 1/sqrt(128)
  int kbeg = q0b - win + 1; if (kbeg < 0) kbeg = 0; kbeg &= ~63;
  const int nt = (q0b + 128 - kbeg) >> 6;

  auto stage = [&](int bi, int k0s){
    unsigned short* Kd = smem + bi*8192;
    unsigned short* Vd = smem + 16384 + bi*8192;
    #pragma unroll
    for (int jj=0;jj<4;jj++){
      int t = (wv*4+jj)*64 + lane;
      int r = t>>4, cc = t&15;
      __builtin_amdgcn_global_load_lds(
        (const __attribute__((address_space(1))) void*)(Kp + (size_t)(k0s+r)*DHEAD + ((cc ^ (r&7))*8)),
        (__attribute__((address_space(3))) void*)(Kd + t*8), 16, 0, 0);
      int dd = t>>7, kq = (t>>3)&15, rr = (t>>1)&3, hb = t&1;
      __builtin_amdgcn_global_load_lds(
        (const __attribute__((address_space(1))) void*)(Vp + (size_t)(k0s + kq*4 + rr)*DHEAD + dd*16 + hb*8),
        (__attribute__((address_space(3))) void*)(Vd + t*8), 16, 0, 0);
    }
  };

  stage(0, kbeg);
  for (int it=0; it<nt; ++it){
    const int k0 = kbeg + it*64;
    const int cur = it & 1;
    __syncthreads();
    if (it+1 < nt) stage(cur^1, k0+64);
    if (k0 <= q0w+31 && (k0 + 63) >= (q0w - win + 1)){
      const unsigned short* Kc = smem + cur*8192;
      f32x4_t s[2][4] = {};
      __builtin_amdgcn_s_setprio(1);
      #pragma unroll
      for (int dt=0;dt<4;dt++){
        bf16x8_t kf[4];
        #pragma unroll
        for (int kb=0;kb<4;kb++){
          int row = kb*16 + qi;
          kf[kb] = *reinterpret_cast<const bf16x8_t*>(Kc + row*128 + (((dt*4+g) ^ (row&7))*8));
        }
        #pragma unroll
        for (int kb=0;kb<4;kb++){
          s[0][kb] = __builtin_amdgcn_mfma_f32_16x16x32_bf16(kf[kb], qf[0][dt], s[0][kb], 0,0,0);
          s[1][kb] = __builtin_amdgcn_mfma_f32_16x16x32_bf16(kf[kb], qf[1][dt], s[1][kb], 0,0,0);
        }
      }
      __builtin_amdgcn_s_setprio(0);
      float4 cb[4];
      #pragma unroll
      for (int kb=0;kb<4;kb++) cb[kb] = *(const float4*)(cF + k0 + kb*16 + 4*g);
      u16x8_t pb[2][2];
      #pragma unroll
      for (int qb=0;qb<2;qb++){
        const int qg = q0w + qb*16 + qi;
        float p[16], tmax = -INFINITY;
        #pragma unroll
        for (int kb=0;kb<4;kb++){
          #pragma unroll
          for (int r=0;r<4;r++){
            int key = k0 + kb*16 + 4*g + r;
            float sv = fmaf(s[qb][kb][r], sm_scale, cFq[qb] - ((const float*)&cb[kb])[r]);
            bool ok = (key <= qg) && (qg - key < win);
            p[kb*4+r] = ok ? sv : -INFINITY;
            tmax = fmaxf(tmax, p[kb*4+r]);
          }
        }
        tmax = fmaxf(tmax, __shfl_xor(tmax, 16, 64));
        tmax = fmaxf(tmax, __shfl_xor(tmax, 32, 64));
        float mnew = fmaxf(mrun[qb], tmax);
        float alpha = __expf(mrun[qb] - mnew);
        float tsum = 0.f;
        #pragma unroll
        for (int i2=0;i2<16;i2++){ p[i2] = __expf(p[i2] - mnew); tsum += p[i2]; }
        tsum += __shfl_xor(tsum, 16, 64);
        tsum += __shfl_xor(tsum, 32, 64);
        lrun[qb] = lrun[qb]*alpha + tsum;
        mrun[qb] = mnew;
        #pragma unroll
        for (int dt=0;dt<8;dt++) ot[qb][dt] *= alpha;
        #pragma unroll
        for (int cc=0;cc<2;cc++){
          #pragma unroll
          for (int e=0;e<8;e++)
            pb[qb][cc][e] = f2bf(p[(2*cc + (e>>2))*4 + (e&3)]);
        }
      }
      unsigned vbase = ldsaddr(smem + 16384 + cur*8192) + lane*8;
      #pragma unroll
      for (int cc=0;cc<2;cc++){
        u16x4_t vlo[8], vhi[8];
        #pragma unroll
        for (int dt=0;dt<8;dt++){
          vlo[dt] = tr16(vbase + (unsigned)((dt*16 + 8*cc)*128));
          vhi[dt] = tr16(vbase + (unsigned)((dt*16 + 8*cc + 4)*128));
        }
        asm volatile("s_waitcnt lgkmcnt(0)");
        __builtin_amdgcn_sched_barrier(0);
        __builtin_amdgcn_s_setprio(1);
        #pragma unroll
        for (int dt=0;dt<8;dt++){
          u16x8_t vv = __builtin_shufflevector(vlo[dt], vhi[dt], 0,1,2,3,4,5,6,7);
          bf16x8_t vf = *reinterpret_cast<bf16x8_t*>(&vv);
          ot[0][dt] = __builtin_amdgcn_mfma_f32_16x16x32_bf16(vf, *reinterpret_cast<bf16x8_t*>(&pb[0][cc]), ot[0][dt], 0,0,0);
          ot[1][dt] = __builtin_amdgcn_mfma_f32_16x16x32_bf16(vf, *reinterpret_cast<bf16x8_t*>(&pb[1][cc]), ot[1][dt], 0,0,0);
        }
        __builtin_amdgcn_s_setprio(0);
      }
    }
  }
  __syncthreads();
  float invl[2] = {1.f/lrun[0], 1.f/lrun[1]};
  #pragma unroll
  for (int qb=0;qb<2;qb++){
    int qlocal = wv*32 + qb*16 + qi;
    #pragma unroll
    for (int dt=0;dt<8;dt++){
      int d8 = dt*2 + (g>>1);
      u16x4_t w;
      #pragma unroll
      for (int r=0;r<4;r++) w[r] = f2bf(ot[qb][dt][r]*invl[qb]);
      *reinterpret_cast<u16x4_t*>(smem + qlocal*128 + ((d8 ^ (qlocal&7))*8) + 4*(g&1)) = w;
    }
  }
  __syncthreads();
  #pragma unroll
  for (int i=0;i<8;i++){
    int t = i*256 + tid;
    int row = t>>4, cc = t&15;
    u16x8_t v = *reinterpret_cast<const u16x8_t*>(smem + row*128 + ((cc ^ (row&7))*8));
    *reinterpret_cast<u16x8_t*>(Y + ((size_t)b*T_SEQ + q0b + row)*CDIM + h*DHEAD + cc*8) = v;
  }
}

extern "C" void kernel_launch(void* const* d_in, const int* in_sizes, int n_in,
                              void* d_out, int out_size, void* d_ws, size_t ws_size,
                              hipStream_t stream){
  const float* x    = (const float*)d_in[0];
  const float* cosT = (const float*)d_in[1];
  const float* sinT = (const float*)d_in[2];
  const float* Wq   = (const float*)d_in[3];
  const float* Wk   = (const float*)d_in[4];
  const float* Wv   = (const float*)d_in[5];
  const float* Wo   = (const float*)d_in[6];
  const float* fgw  = (const float*)d_in[7];
  const float* fgb  = (const float*)d_in[8];
  const float* wlam = (const float*)d_in[9];
  const int*   winp = (const int*)d_in[10];

  char* ws = (char*)d_ws;
  unsigned short* xb    = (unsigned short*)(ws + 0);          // 16 MB
  unsigned short* WqkvT = (unsigned short*)(ws + 16777216);   // 24 MB [6144][2048] bf16 (N,K)
  unsigned short* WoT   = (unsigned short*)(ws + 41943040);   // 8 MB
  unsigned short* QKVh  = (unsigned short*)(ws + 50331648);   // 48 MB: Q|K|V each (B,H,T,D)
  unsigned short* Qh = QKVh;
  unsigned short* Kh = QKVh + 8388608;
  unsigned short* Vh = QKVh + 16777216;
  unsigned short* Yb  = (unsigned short*)(ws + 100663296);    // 16 MB
  float* lfg  = (float*)(ws + 117440512);                     // 256 KB
  float* cumF = (float*)(ws + 117702656);                     // 256 KB

  cast_f32_bf16<<<4096, 256, 0, stream>>>(x, xb, BT*CDIM);
  dim3 tgrid(64,64), tblk(32,8);
  transpose_cast<<<tgrid, tblk, 0, stream>>>(Wq, WqkvT);
  transpose_cast<<<tgrid, tblk, 0, stream>>>(Wk, WqkvT + 4194304);
  transpose_cast<<<tgrid, tblk, 0, stream>>>(Wv, WqkvT + 8388608);
  transpose_cast<<<tgrid, tblk, 0, stream>>>(Wo, WoT);

  hipError_t attr_ok = hipFuncSetAttribute(
      reinterpret_cast<const void*>(&gemm256<1>),
      hipFuncAttributeMaxDynamicSharedMemorySize, 131072);
  if (attr_ok == hipSuccess){
    gemm256<1><<<(BT/256)*(NQKV/256), 512, 131072, stream>>>(xb, WqkvT, QKVh, BT, NQKV, CDIM);
  } else {
    gemm_bt<1><<<dim3(NQKV/128, BT/128), 256, 0, stream>>>(xb, WqkvT, QKVh, BT, NQKV, CDIM);
  }

  gates_kernel<<<BT, 256, 0, stream>>>(x, fgw, fgb, wlam, lfg);
  cumsum_kernel<<<BHT, 256, 0, stream>>>(lfg, cumF);

  rope_rms<<<BHT*T_SEQ/4, 256, 0, stream>>>(Qh, cosT, sinT);
  rope_rms<<<BHT*T_SEQ/4, 256, 0, stream>>>(Kh, cosT, sinT);

  attn_kernel<<<dim3(16, BHT), 256, 0, stream>>>(Qh, Kh, Vh, cumF, Yb, winp);

  gemm_bt<2><<<dim3(CDIM/128, BT/128), 256, 0, stream>>>(Yb, WoT, d_out, BT, CDIM, CDIM);
}

// Round 5
// 355.612 us; speedup vs baseline: 1.6640x; 1.0529x over previous
//
#include <hip/hip_runtime.h>
#include <hip/hip_bf16.h>
#include <stdint.h>

#define T_SEQ 2048
#define CDIM  2048
#define NHEAD 16
#define DHEAD 128
#define BT    4096   // B*T
#define BHT   32     // B*H
#define NQKV  6144

typedef __bf16 bf16x8_t __attribute__((ext_vector_type(8)));
typedef float  f32x4_t  __attribute__((ext_vector_type(4)));
typedef unsigned short u16x8_t __attribute__((ext_vector_type(8)));
typedef unsigned short u16x4_t __attribute__((ext_vector_type(4)));

__device__ __forceinline__ unsigned short f2bf(float f){
  unsigned int u = __float_as_uint(f);
  u += 0x7fffu + ((u >> 16) & 1u);
  return (unsigned short)(u >> 16);
}
__device__ __forceinline__ float bf2f(unsigned short h){
  return __uint_as_float(((unsigned int)h) << 16);
}
__device__ __forceinline__ unsigned ldsaddr(const void* p){
  return (unsigned)(size_t)(const __attribute__((address_space(3))) void*)p;
}
__device__ __forceinline__ u16x4_t tr16(unsigned a){
  u16x4_t r;
  asm volatile("ds_read_b64_tr_b16 %0, %1" : "=v"(r) : "v"(a));
  return r;
}

// ---------------- cast x (f32 -> bf16) ----------------
__global__ __launch_bounds__(256) void cast_f32_bf16(const float* __restrict__ in,
                                                     unsigned short* __restrict__ out, int n){
  int i = (blockIdx.x*256 + threadIdx.x)*8;
  if (i >= n) return;
  float4 a = *(const float4*)(in + i);
  float4 b = *(const float4*)(in + i + 4);
  u16x8_t o;
  o[0]=f2bf(a.x); o[1]=f2bf(a.y); o[2]=f2bf(a.z); o[3]=f2bf(a.w);
  o[4]=f2bf(b.x); o[5]=f2bf(b.y); o[6]=f2bf(b.z); o[7]=f2bf(b.w);
  *(u16x8_t*)(out + i) = o;
}

// ---------------- transpose + cast W (f32 [K][N] -> bf16 [N][K]) ----------------
__global__ __launch_bounds__(256) void transpose_cast(const float* __restrict__ W,
                                                      unsigned short* __restrict__ Wt){
  __shared__ float tile[32][33];
  int n0 = blockIdx.x*32, k0 = blockIdx.y*32;
  int tx = threadIdx.x, ty = threadIdx.y;  // 32 x 8
  #pragma unroll
  for (int i=0;i<32;i+=8)
    tile[ty+i][tx] = W[(size_t)(k0+ty+i)*CDIM + n0 + tx];
  __syncthreads();
  #pragma unroll
  for (int i=0;i<32;i+=8)
    Wt[(size_t)(n0+ty+i)*CDIM + k0 + tx] = f2bf(tile[tx][ty+i]);
}

// ========== 256x128 ring-4 uniform-phase GEMM (T2+T4+T5, tail-free grids) ==========
// C[M][N] = A[M][K] * Bt[N][K]^T.  BM=256, BN=128, BK=32, 4 LDS buffers.
// 512 thr = 8 waves (2M x 4N): per-wave 128x32 out = acc[8][2].
// Phase t: read buf t%4 (10 ds_read_b128), stage tile t+3 into buf (t+3)%4
// (3 glds/thread), barrier, lgkmcnt(0), 16 MFMA, vmcnt(6), barrier.
// Residency: tile t+1's 3 loads are the oldest of 9 outstanding -> vmcnt(6).
// Buffer overwrite safety: buf (t+3)%4 last read in phase t-1, whose ds_reads
// completed (lgkmcnt(0)) before its end barrier; glds issued after it.
// LDS swizzle: 16B granule gs at row r holds logical granule gs^((r>>1)&3);
// read-side XOR identical => max 2-way bank aliasing (free).
// LDS u16 map per buf (12288 u16 = 24 KB): A slots [0,1024)*8, B 8192+[0,512)*8.

#define V2_SYNC() do{ __builtin_amdgcn_sched_barrier(0); \
  __builtin_amdgcn_s_barrier(); \
  asm volatile("s_waitcnt lgkmcnt(0)" ::: "memory"); \
  __builtin_amdgcn_sched_barrier(0); }while(0)

#define V2_TAIL() do{ asm volatile("s_waitcnt vmcnt(6)" ::: "memory"); \
  __builtin_amdgcn_sched_barrier(0); \
  __builtin_amdgcn_s_barrier(); }while(0)

#define V2_MFMA() do{ __builtin_amdgcn_s_setprio(1); \
  _Pragma("unroll") for (int mi=0;mi<8;mi++) \
  _Pragma("unroll") for (int ni=0;ni<2;ni++) \
    acc[mi][ni] = __builtin_amdgcn_mfma_f32_16x16x32_bf16(af[mi], bfr[ni], acc[mi][ni],0,0,0); \
  __builtin_amdgcn_s_setprio(0); }while(0)

#define V2_PHASE(BUF, TIDX) do{ \
  readA(BUF); readB(BUF); \
  { int ts_ = (TIDX)+3; if (ts_ > ntm1) ts_ = ntm1; stage(((BUF)+3)&3, ts_); } \
  V2_SYNC(); V2_MFMA(); V2_TAIL(); }while(0)

template<int MODE>
__global__ __launch_bounds__(512, 2) void gemm_v2(const unsigned short* __restrict__ A,
                                                  const unsigned short* __restrict__ Bt,
                                                  void* __restrict__ Cout,
                                                  int M, int N, int K){
  extern __shared__ unsigned short lds[];
  const int nx = N >> 7;
  const int nwg = (M >> 8) * nx;
  const int bid = blockIdx.x;
  const int wg = (bid & 7)*(nwg >> 3) + (bid >> 3);   // nwg % 8 == 0
  const int m0 = (wg / nx) << 8, n0 = (wg % nx) << 7;
  const int tid = threadIdx.x, lane = tid & 63, wv = tid >> 6;
  const int wm = wv >> 2, wn = wv & 3;
  const int g = lane >> 4, qi = lane & 15;
  const int nt = K >> 5, ntm1 = (K >> 5) - 1;

  f32x4_t acc[8][2] = {};
  bf16x8_t af[8], bfr[2];

  // staging slot precompute: A slots {tid, tid+512}, B slot {tid}
  // slot s: row = s>>2, phys granule = s&3, logical gran = (s&3)^((row>>1)&3)
  int goffA[2], goffB;
  #pragma unroll
  for (int j=0;j<2;j++){
    int s = j*512 + tid;
    int row = s >> 2;
    int lg = (s & 3) ^ ((row >> 1) & 3);
    goffA[j] = row*K + lg*8;
  }
  { int s = tid; int row = s >> 2; int lg = (s & 3) ^ ((row >> 1) & 3);
    goffB = row*K + lg*8; }

  auto stage = [&](int buf, int kt){
    const unsigned short* srcA = A + (size_t)m0*K + kt*32;
    const unsigned short* srcB = Bt + (size_t)n0*K + kt*32;
    unsigned short* base = lds + buf*12288;
    #pragma unroll
    for (int j=0;j<2;j++)
      __builtin_amdgcn_global_load_lds(
        (const __attribute__((address_space(1))) void*)(srcA + goffA[j]),
        (__attribute__((address_space(3))) void*)(base + (j*512 + tid)*8), 16, 0, 0);
    __builtin_amdgcn_global_load_lds(
        (const __attribute__((address_space(1))) void*)(srcB + goffB),
        (__attribute__((address_space(3))) void*)(base + 8192 + tid*8), 16, 0, 0);
  };
  auto readA = [&](int buf){
    const unsigned short* base = lds + buf*12288;
    #pragma unroll
    for (int mi=0;mi<8;mi++){
      int row = wm*128 + mi*16 + qi;
      int gs = g ^ ((row >> 1) & 3);
      af[mi] = *reinterpret_cast<const bf16x8_t*>(base + (row*4 + gs)*8);
    }
  };
  auto readB = [&](int buf){
    const unsigned short* base = lds + buf*12288 + 8192;
    #pragma unroll
    for (int ni=0;ni<2;ni++){
      int row = wn*32 + ni*16 + qi;
      int gs = g ^ ((row >> 1) & 3);
      bfr[ni] = *reinterpret_cast<const bf16x8_t*>(base + (row*4 + gs)*8);
    }
  };

  // prologue: tiles 0,1,2 -> bufs 0,1,2 (9 loads/thread); drain tile 0
  stage(0,0); stage(1,1); stage(2,2);
  asm volatile("s_waitcnt vmcnt(6)" ::: "memory");
  __builtin_amdgcn_sched_barrier(0);
  __builtin_amdgcn_s_barrier();

  const int niter = nt >> 2;   // nt % 4 == 0 (K=2048 -> 64 tiles, 16 iters)
  for (int it=0; it<niter; ++it){
    const int t4 = it*4;
    V2_PHASE(0, t4+0);
    V2_PHASE(1, t4+1);
    V2_PHASE(2, t4+2);
    V2_PHASE(3, t4+3);
  }

  // epilogue: scatter C
  #pragma unroll
  for (int mi=0;mi<8;mi++){
    #pragma unroll
    for (int ni=0;ni<2;ni++){
      #pragma unroll
      for (int r=0;r<4;r++){
        int mm = m0 + wm*128 + mi*16 + 4*g + r;
        int nn = n0 + wn*32  + ni*16 + qi;
        float v = acc[mi][ni][r];
        if (MODE == 2){
          ((float*)Cout)[(size_t)mm*N + nn] = v;
        } else {
          int bb2 = mm >> 11, t = mm & (T_SEQ-1);
          int which = nn >> 11;             // 0=Q 1=K 2=V
          int hh = (nn >> 7) & 15, d = nn & (DHEAD-1);
          ((unsigned short*)Cout)[(size_t)which*8388608 +
              (((size_t)bb2*NHEAD + hh)*T_SEQ + t)*DHEAD + d] = f2bf(v);
        }
      }
    }
  }
}

// ---------------- bf16 MFMA GEMM 128^2 (m97 structure): fallback only ----------------
template<int MODE>
__global__ __launch_bounds__(256) void gemm_bt(const unsigned short* __restrict__ A,
                                               const unsigned short* __restrict__ Bt,
                                               void* __restrict__ Cout,
                                               int M, int N, int K){
  __shared__ unsigned short As[128*32];
  __shared__ unsigned short Bs[128*32];
  const int nx = gridDim.x;
  const int nwg = nx * gridDim.y;
  const int d0 = blockIdx.y*nx + blockIdx.x;
  const int wg = (d0 & 7)*(nwg >> 3) + (d0 >> 3);
  const int m0 = (wg / nx)*128, n0 = (wg % nx)*128;
  const int tid = threadIdx.x;
  const int lane = tid & 63, wv = tid >> 6;
  const int g = lane >> 4, qi = lane & 15;
  const int wm = (wv >> 1)*64, wn = (wv & 1)*64;
  f32x4_t acc[4][4] = {};
  for (int k0 = 0; k0 < K; k0 += 32){
    __syncthreads();
    #pragma unroll
    for (int i=0;i<2;i++){
      int ci = i*256 + tid;
      int row = ci >> 2, kc = ci & 3;
      __builtin_amdgcn_global_load_lds(
        (const __attribute__((address_space(1))) void*)(A + (size_t)(m0+row)*K + k0 + kc*8),
        (__attribute__((address_space(3))) void*)(As + ci*8), 16, 0, 0);
      __builtin_amdgcn_global_load_lds(
        (const __attribute__((address_space(1))) void*)(Bt + (size_t)(n0+row)*K + k0 + kc*8),
        (__attribute__((address_space(3))) void*)(Bs + ci*8), 16, 0, 0);
    }
    __syncthreads();
    bf16x8_t af[4], bfr[4];
    #pragma unroll
    for (int mi=0;mi<4;mi++)
      af[mi] = *reinterpret_cast<const bf16x8_t*>(As + (wm + mi*16 + qi)*32 + g*8);
    #pragma unroll
    for (int ni=0;ni<4;ni++)
      bfr[ni] = *reinterpret_cast<const bf16x8_t*>(Bs + (wn + ni*16 + qi)*32 + g*8);
    #pragma unroll
    for (int mi=0;mi<4;mi++){
      #pragma unroll
      for (int ni=0;ni<4;ni++){
        acc[mi][ni] = __builtin_amdgcn_mfma_f32_16x16x32_bf16(af[mi], bfr[ni], acc[mi][ni], 0, 0, 0);
      }
    }
  }
  #pragma unroll
  for (int mi=0;mi<4;mi++){
    #pragma unroll
    for (int ni=0;ni<4;ni++){
      #pragma unroll
      for (int r=0;r<4;r++){
        int mm = m0 + wm + mi*16 + 4*g + r;
        int nn = n0 + wn + ni*16 + qi;
        float v = acc[mi][ni][r];
        if (MODE == 2){
          ((float*)Cout)[(size_t)mm*N + nn] = v;
        } else {
          int b = mm >> 11, t = mm & (T_SEQ-1);
          int which = nn >> 11;
          int hh = (nn >> 7) & 15, d = nn & (DHEAD-1);
          ((unsigned short*)Cout)[(size_t)which*8388608 +
              (((size_t)b*NHEAD + hh)*T_SEQ + t)*DHEAD + d] = f2bf(v);
        }
      }
    }
  }
}

// ---------------- gates: lam/logit/log_fgate per (b,t,h) ----------------
__global__ __launch_bounds__(256) void gates_kernel(const float* __restrict__ x,
    const float* __restrict__ fgw, const float* __restrict__ fgb,
    const float* __restrict__ wlam, float* __restrict__ lfg){
  __shared__ float xs[2048];
  __shared__ float part[256];
  const int row = blockIdx.x;     // b*T + t
  const int tid = threadIdx.x;
  const float* xp = x + (size_t)row*CDIM;
  #pragma unroll
  for (int i=0;i<2;i++)
    *(float4*)(xs + (i*256+tid)*4) = *(const float4*)(xp + (i*256+tid)*4);
  __syncthreads();
  const int col = tid & 31;       // 0-15: fgate, 16-31: lambda
  const int seg = tid >> 5;       // 0..7
  const float* W = (col < 16) ? fgw : wlam;
  const int h = col & 15;
  float acc = 0.f;
  for (int k = seg*256; k < seg*256 + 256; ++k)
    acc = fmaf(xs[k], W[k*16 + h], acc);
  part[tid] = acc;
  __syncthreads();
  for (int s=4; s>=1; s>>=1){
    if (seg < s) part[tid] += part[tid + s*32];
    __syncthreads();
  }
  if (tid < 16){
    float df = part[tid];
    float dl = part[16 + tid];
    float lam = (dl > 0.f) ? (dl + 1.f) : __expf(dl);   // elu + 1
    float logit = (df + fgb[tid]) * lam;
    float ls = fminf(logit, 0.f) - log1pf(__expf(-fabsf(logit))); // log_sigmoid
    float lf = ls / (lam + 0.001f);
    int b = row >> 11, t = row & (T_SEQ-1);
    lfg[((size_t)b*NHEAD + tid)*T_SEQ + t] = lf;
  }
}

// ---------------- inclusive cumsum along T per (b,h) ----------------
__global__ __launch_bounds__(256) void cumsum_kernel(const float* __restrict__ lfg,
                                                     float* __restrict__ cumF){
  __shared__ float sums[256];
  const int bh = blockIdx.x;
  const float* in = lfg + (size_t)bh*T_SEQ;
  float* out = cumF + (size_t)bh*T_SEQ;
  const int tid = threadIdx.x;
  float4 a = *(const float4*)(in + tid*8);
  float4 b = *(const float4*)(in + tid*8 + 4);
  float v[8] = {a.x,a.y,a.z,a.w,b.x,b.y,b.z,b.w};
  float run = 0.f;
  #pragma unroll
  for (int e=0;e<8;e++) run += v[e];
  sums[tid] = run;
  __syncthreads();
  for (int off=1; off<256; off<<=1){
    float y = (tid >= off) ? sums[tid-off] : 0.f;
    __syncthreads();
    sums[tid] += y;
    __syncthreads();
  }
  float acc = sums[tid] - run;  // exclusive prefix
  float o[8];
  #pragma unroll
  for (int e=0;e<8;e++){ acc += v[e]; o[e] = acc; }
  *(float4*)(out + tid*8)     = make_float4(o[0],o[1],o[2],o[3]);
  *(float4*)(out + tid*8 + 4) = make_float4(o[4],o[5],o[6],o[7]);
}

// ---------------- in-place RoPE + RMSNorm on (B*H, T, D) bf16 ----------------
__global__ __launch_bounds__(256) void rope_rms(unsigned short* __restrict__ X,
    const float* __restrict__ cosT, const float* __restrict__ sinT){
  const int tid = threadIdx.x, lane = tid & 63, wv = tid >> 6;
  const int idx = blockIdx.x*4 + wv;        // (b*H + h)*T + t
  const int t = idx & (T_SEQ-1);
  unsigned short* xp = X + (size_t)idx*DHEAD;
  float x1 = bf2f(xp[lane]);
  float x2 = bf2f(xp[lane+64]);
  float c = cosT[t*64 + lane];
  float s = sinT[t*64 + lane];
  float o1 = x1*c + x2*s;
  float o2 = x2*c - x1*s;
  float ss = o1*o1 + o2*o2;
  #pragma unroll
  for (int off=1; off<64; off<<=1) ss += __shfl_xor(ss, off, 64);
  float scale = rsqrtf(ss*(1.f/128.f) + 1.1920929e-07f);
  xp[lane]    = f2bf(o1*scale);
  xp[lane+64] = f2bf(o2*scale);
}

// ---------------- windowed gated attention ----------------
// grid (16, 32) -> XCD-swizzled to (qtile, bh); 256 thr = 4 waves x 32 queries.
// KVBLK=64 double-buffered: K linear+XOR-swz [64][128], V subtiled [8][16][4][16] for tr16.
__global__ __launch_bounds__(256, 2) void attn_kernel(const unsigned short* __restrict__ Qh,
    const unsigned short* __restrict__ Kh, const unsigned short* __restrict__ Vh,
    const float* __restrict__ cumF, unsigned short* __restrict__ Y,
    const int* __restrict__ winp){
  __shared__ unsigned short smem[32768];     // 64 KB: K0|K1|V0|V1 (8192 elems each)
  const int dlin = blockIdx.y*16 + blockIdx.x;
  const int c8 = dlin & 7, klin = dlin >> 3;
  const int bh = c8 + 8*(klin >> 4);
  const int q0b = (klin & 15)*128;
  const int b = bh >> 4, h = bh & 15;
  const int tid = threadIdx.x, lane = tid & 63, wv = tid >> 6;
  const int g = lane >> 4, qi = lane & 15;
  const int win = *winp;
  const unsigned short* Qp = Qh + (size_t)bh*T_SEQ*DHEAD;
  const unsigned short* Kp = Kh + (size_t)bh*T_SEQ*DHEAD;
  const unsigned short* Vp = Vh + (size_t)bh*T_SEQ*DHEAD;
  const float* cF = cumF + (size_t)bh*T_SEQ;
  const int q0w = q0b + wv*32;
  bf16x8_t qf[2][4];
  float cFq[2];
  #pragma unroll
  for (int qb=0;qb<2;qb++){
    cFq[qb] = cF[q0w + qb*16 + qi];
    #pragma unroll
    for (int dt=0;dt<4;dt++)
      qf[qb][dt] = *reinterpret_cast<const bf16x8_t*>(Qp + (size_t)(q0w + qb*16 + qi)*DHEAD + dt*32 + g*8);
  }
  f32x4_t ot[2][8] = {};
  float mrun[2] = {-1e30f, -1e30f}, lrun[2] = {0.f, 0.f};
  const float sm_scale = 0.08838834764831845f;  // 1/sqrt(128)
  int kbeg = q0b - win + 1; if (kbeg < 0) kbeg = 0; kbeg &= ~63;
  const int nt = (q0b + 128 - kbeg) >> 6;

  auto stage = [&](int bi, int k0s){
    unsigned short* Kd = smem + bi*8192;
    unsigned short* Vd = smem + 16384 + bi*8192;
    #pragma unroll
    for (int jj=0;jj<4;jj++){
      int t = (wv*4+jj)*64 + lane;
      int r = t>>4, cc = t&15;
      __builtin_amdgcn_global_load_lds(
        (const __attribute__((address_space(1))) void*)(Kp + (size_t)(k0s+r)*DHEAD + ((cc ^ (r&7))*8)),
        (__attribute__((address_space(3))) void*)(Kd + t*8), 16, 0, 0);
      int dd = t>>7, kq = (t>>3)&15, rr = (t>>1)&3, hb = t&1;
      __builtin_amdgcn_global_load_lds(
        (const __attribute__((address_space(1))) void*)(Vp + (size_t)(k0s + kq*4 + rr)*DHEAD + dd*16 + hb*8),
        (__attribute__((address_space(3))) void*)(Vd + t*8), 16, 0, 0);
    }
  };

  stage(0, kbeg);
  for (int it=0; it<nt; ++it){
    const int k0 = kbeg + it*64;
    const int cur = it & 1;
    __syncthreads();
    if (it+1 < nt) stage(cur^1, k0+64);
    if (k0 <= q0w+31 && (k0 + 63) >= (q0w - win + 1)){
      const unsigned short* Kc = smem + cur*8192;
      f32x4_t s[2][4] = {};
      __builtin_amdgcn_s_setprio(1);
      #pragma unroll
      for (int dt=0;dt<4;dt++){
        bf16x8_t kf[4];
        #pragma unroll
        for (int kb=0;kb<4;kb++){
          int row = kb*16 + qi;
          kf[kb] = *reinterpret_cast<const bf16x8_t*>(Kc + row*128 + (((dt*4+g) ^ (row&7))*8));
        }
        #pragma unroll
        for (int kb=0;kb<4;kb++){
          s[0][kb] = __builtin_amdgcn_mfma_f32_16x16x32_bf16(kf[kb], qf[0][dt], s[0][kb], 0,0,0);
          s[1][kb] = __builtin_amdgcn_mfma_f32_16x16x32_bf16(kf[kb], qf[1][dt], s[1][kb], 0,0,0);
        }
      }
      __builtin_amdgcn_s_setprio(0);
      float4 cb[4];
      #pragma unroll
      for (int kb=0;kb<4;kb++) cb[kb] = *(const float4*)(cF + k0 + kb*16 + 4*g);
      u16x8_t pb[2][2];
      #pragma unroll
      for (int qb=0;qb<2;qb++){
        const int qg = q0w + qb*16 + qi;
        float p[16], tmax = -INFINITY;
        #pragma unroll
        for (int kb=0;kb<4;kb++){
          #pragma unroll
          for (int r=0;r<4;r++){
            int key = k0 + kb*16 + 4*g + r;
            float sv = fmaf(s[qb][kb][r], sm_scale, cFq[qb] - ((const float*)&cb[kb])[r]);
            bool ok = (key <= qg) && (qg - key < win);
            p[kb*4+r] = ok ? sv : -INFINITY;
            tmax = fmaxf(tmax, p[kb*4+r]);
          }
        }
        tmax = fmaxf(tmax, __shfl_xor(tmax, 16, 64));
        tmax = fmaxf(tmax, __shfl_xor(tmax, 32, 64));
        float mnew = fmaxf(mrun[qb], tmax);
        float alpha = __expf(mrun[qb] - mnew);
        float tsum = 0.f;
        #pragma unroll
        for (int i2=0;i2<16;i2++){ p[i2] = __expf(p[i2] - mnew); tsum += p[i2]; }
        tsum += __shfl_xor(tsum, 16, 64);
        tsum += __shfl_xor(tsum, 32, 64);
        lrun[qb] = lrun[qb]*alpha + tsum;
        mrun[qb] = mnew;
        #pragma unroll
        for (int dt=0;dt<8;dt++) ot[qb][dt] *= alpha;
        #pragma unroll
        for (int cc=0;cc<2;cc++){
          #pragma unroll
          for (int e=0;e<8;e++)
            pb[qb][cc][e] = f2bf(p[(2*cc + (e>>2))*4 + (e&3)]);
        }
      }
      unsigned vbase = ldsaddr(smem + 16384 + cur*8192) + lane*8;
      #pragma unroll
      for (int cc=0;cc<2;cc++){
        u16x4_t vlo[8], vhi[8];
        #pragma unroll
        for (int dt=0;dt<8;dt++){
          vlo[dt] = tr16(vbase + (unsigned)((dt*16 + 8*cc)*128));
          vhi[dt] = tr16(vbase + (unsigned)((dt*16 + 8*cc + 4)*128));
        }
        asm volatile("s_waitcnt lgkmcnt(0)");
        __builtin_amdgcn_sched_barrier(0);
        __builtin_amdgcn_s_setprio(1);
        #pragma unroll
        for (int dt=0;dt<8;dt++){
          u16x8_t vv = __builtin_shufflevector(vlo[dt], vhi[dt], 0,1,2,3,4,5,6,7);
          bf16x8_t vf = *reinterpret_cast<bf16x8_t*>(&vv);
          ot[0][dt] = __builtin_amdgcn_mfma_f32_16x16x32_bf16(vf, *reinterpret_cast<bf16x8_t*>(&pb[0][cc]), ot[0][dt], 0,0,0);
          ot[1][dt] = __builtin_amdgcn_mfma_f32_16x16x32_bf16(vf, *reinterpret_cast<bf16x8_t*>(&pb[1][cc]), ot[1][dt], 0,0,0);
        }
        __builtin_amdgcn_s_setprio(0);
      }
    }
  }
  __syncthreads();
  float invl[2] = {1.f/lrun[0], 1.f/lrun[1]};
  #pragma unroll
  for (int qb=0;qb<2;qb++){
    int qlocal = wv*32 + qb*16 + qi;
    #pragma unroll
    for (int dt=0;dt<8;dt++){
      int d8 = dt*2 + (g>>1);
      u16x4_t w;
      #pragma unroll
      for (int r=0;r<4;r++) w[r] = f2bf(ot[qb][dt][r]*invl[qb]);
      *reinterpret_cast<u16x4_t*>(smem + qlocal*128 + ((d8 ^ (qlocal&7))*8) + 4*(g&1)) = w;
    }
  }
  __syncthreads();
  #pragma unroll
  for (int i=0;i<8;i++){
    int t = i*256 + tid;
    int row = t>>4, cc = t&15;
    u16x8_t v = *reinterpret_cast<const u16x8_t*>(smem + row*128 + ((cc ^ (row&7))*8));
    *reinterpret_cast<u16x8_t*>(Y + ((size_t)b*T_SEQ + q0b + row)*CDIM + h*DHEAD + cc*8) = v;
  }
}

extern "C" void kernel_launch(void* const* d_in, const int* in_sizes, int n_in,
                              void* d_out, int out_size, void* d_ws, size_t ws_size,
                              hipStream_t stream){
  const float* x    = (const float*)d_in[0];
  const float* cosT = (const float*)d_in[1];
  const float* sinT = (const float*)d_in[2];
  const float* Wq   = (const float*)d_in[3];
  const float* Wk   = (const float*)d_in[4];
  const float* Wv   = (const float*)d_in[5];
  const float* Wo   = (const float*)d_in[6];
  const float* fgw  = (const float*)d_in[7];
  const float* fgb  = (const float*)d_in[8];
  const float* wlam = (const float*)d_in[9];
  const int*   winp = (const int*)d_in[10];

  char* ws = (char*)d_ws;
  unsigned short* xb    = (unsigned short*)(ws + 0);          // 16 MB
  unsigned short* WqkvT = (unsigned short*)(ws + 16777216);   // 24 MB [6144][2048] bf16 (N,K)
  unsigned short* WoT   = (unsigned short*)(ws + 41943040);   // 8 MB
  unsigned short* QKVh  = (unsigned short*)(ws + 50331648);   // 48 MB: Q|K|V each (B,H,T,D)
  unsigned short* Qh = QKVh;
  unsigned short* Kh = QKVh + 8388608;
  unsigned short* Vh = QKVh + 16777216;
  unsigned short* Yb  = (unsigned short*)(ws + 100663296);    // 16 MB
  float* lfg  = (float*)(ws + 117440512);                     // 256 KB
  float* cumF = (float*)(ws + 117702656);                     // 256 KB

  cast_f32_bf16<<<4096, 256, 0, stream>>>(x, xb, BT*CDIM);
  dim3 tgrid(64,64), tblk(32,8);
  transpose_cast<<<tgrid, tblk, 0, stream>>>(Wq, WqkvT);
  transpose_cast<<<tgrid, tblk, 0, stream>>>(Wk, WqkvT + 4194304);
  transpose_cast<<<tgrid, tblk, 0, stream>>>(Wv, WqkvT + 8388608);
  transpose_cast<<<tgrid, tblk, 0, stream>>>(Wo, WoT);

  hipError_t a1 = hipFuncSetAttribute(
      reinterpret_cast<const void*>(&gemm_v2<1>),
      hipFuncAttributeMaxDynamicSharedMemorySize, 98304);
  hipError_t a2 = hipFuncSetAttribute(
      reinterpret_cast<const void*>(&gemm_v2<2>),
      hipFuncAttributeMaxDynamicSharedMemorySize, 98304);

  if (a1 == hipSuccess){
    gemm_v2<1><<<(BT/256)*(NQKV/128), 512, 98304, stream>>>(xb, WqkvT, QKVh, BT, NQKV, CDIM);
  } else {
    gemm_bt<1><<<dim3(NQKV/128, BT/128), 256, 0, stream>>>(xb, WqkvT, QKVh, BT, NQKV, CDIM);
  }

  gates_kernel<<<BT, 256, 0, stream>>>(x, fgw, fgb, wlam, lfg);
  cumsum_kernel<<<BHT, 256, 0, stream>>>(lfg, cumF);

  rope_rms<<<BHT*T_SEQ/4, 256, 0, stream>>>(Qh, cosT, sinT);
  rope_rms<<<BHT*T_SEQ/4, 256, 0, stream>>>(Kh, cosT, sinT);

  attn_kernel<<<dim3(16, BHT), 256, 0, stream>>>(Qh, Kh, Vh, cumF, Yb, winp);

  if (a2 == hipSuccess){
    gemm_v2<2><<<(BT/256)*(CDIM/128), 512, 98304, stream>>>(Yb, WoT, d_out, BT, CDIM, CDIM);
  } else {
    gemm_bt<2><<<dim3(CDIM/128, BT/128), 256, 0, stream>>>(Yb, WoT, d_out, BT, CDIM, CDIM);
  }
}